// Round 8
// baseline (285.456 us; speedup 1.0000x reference)
//
#include <hip/hip_runtime.h>
#include <math.h>

// Problem constants
#define NB   8
#define NPIX 4096          // H*W
#define MROW 32768         // B*H*W
#define CV_  256
#define TT   77
#define CT_  512
#define NH_  8
#define DH_  32
#define BT_  616           // B*T

typedef __bf16 bf16x8 __attribute__((ext_vector_type(8)));
typedef float  f32x4  __attribute__((ext_vector_type(4)));

__device__ __forceinline__ float bf2f(unsigned short u) {
  return __uint_as_float(((unsigned)u) << 16);
}
__device__ __forceinline__ unsigned short f2b(float f) {
  unsigned u = __float_as_uint(f);
  return (unsigned short)((u + 0x7FFFu + ((u >> 16) & 1u)) >> 16);
}
__device__ __forceinline__ unsigned pack2(float lo, float hi) {
  return ((unsigned)f2b(hi) << 16) | (unsigned)f2b(lo);
}
__device__ __forceinline__ void async_copy16(const unsigned short* g,
                                             unsigned short* l) {
  __builtin_amdgcn_global_load_lds(
      (const __attribute__((address_space(1))) void*)g,
      (__attribute__((address_space(3))) void*)l, 16, 0, 0);
}
// tanh-GELU: 0.5*v*(1+tanh(0.79788456*(v+0.044715 v^3))) = v - v/(e^{2u}+1)
__device__ __forceinline__ float gelu_t(float v) {
  float p = v * fmaf(0.0713548162726f, v * v, 1.59576912161f);
  float e = __expf(p);
  return v - v / (e + 1.0f);
}

// -- prep: LN1 (0..8191) + LDS-tiled weight convT (8192..8415) +
//          kv bias (8416) + pad mask (8417..8570) --------------------------
__global__ __launch_bounds__(256) void prep_kernel(
    const float* __restrict__ visual, const float* __restrict__ g1,
    const float* __restrict__ b1, unsigned short* __restrict__ xbuf,
    const float* __restrict__ s0, const float* __restrict__ s1,
    const float* __restrict__ s2, const float* __restrict__ s3,
    const float* __restrict__ s4, const float* __restrict__ s5,
    unsigned short* __restrict__ d0, unsigned short* __restrict__ d1,
    unsigned short* __restrict__ d2, unsigned short* __restrict__ d3,
    unsigned short* __restrict__ d4, unsigned short* __restrict__ d5,
    const float* __restrict__ bk, const float* __restrict__ bv,
    float* __restrict__ bkv, const float* __restrict__ text,
    float* __restrict__ padb) {
  __shared__ unsigned short tl[64 * 68];   // 8704 B transpose tile
  int bx = blockIdx.x;
  int tid = threadIdx.x;
  int wave = tid >> 6, lane = tid & 63;
  if (bx < 8192) {                       // LN1: visual fp32 -> x bf16
    int row = bx * 4 + wave;
    size_t base = (size_t)row * 256 + lane * 4;
    float4 f = *reinterpret_cast<const float4*>(visual + base);
    float v0 = f.x, v1 = f.y, v2 = f.z, v3 = f.w;
    float s = v0 + v1 + v2 + v3;
    float q = v0 * v0 + v1 * v1 + v2 * v2 + v3 * v3;
#pragma unroll
    for (int off = 1; off < 64; off <<= 1) {
      s += __shfl_xor(s, off);
      q += __shfl_xor(q, off);
    }
    float mean = s * (1.0f / 256.0f);
    float var  = q * (1.0f / 256.0f) - mean * mean;
    float rstd = rsqrtf(var + 1e-5f);
    float4 gv = *reinterpret_cast<const float4*>(g1 + lane * 4);
    float4 bv4 = *reinterpret_cast<const float4*>(b1 + lane * 4);
    ushort4 o;
    o.x = f2b((v0 - mean) * rstd * gv.x + bv4.x);
    o.y = f2b((v1 - mean) * rstd * gv.y + bv4.y);
    o.z = f2b((v2 - mean) * rstd * gv.z + bv4.z);
    o.w = f2b((v3 - mean) * rstd * gv.w + bv4.w);
    *reinterpret_cast<ushort4*>(xbuf + base) = o;
    return;
  }
  if (bx < 8416) {                       // LDS-tiled 64x64 transpose
    int ti = bx - 8192;                  // 0..223
    const float* src; unsigned short* dst; int R, C, m;
    if      (ti < 16)  { src = s0; dst = d0; R = 256;  C = 256;  m = ti; }
    else if (ti < 48)  { src = s1; dst = d1; R = 512;  C = 256;  m = ti - 16; }
    else if (ti < 80)  { src = s2; dst = d2; R = 512;  C = 256;  m = ti - 48; }
    else if (ti < 96)  { src = s3; dst = d3; R = 256;  C = 256;  m = ti - 80; }
    else if (ti < 160) { src = s4; dst = d4; R = 256;  C = 1024; m = ti - 96; }
    else               { src = s5; dst = d5; R = 1024; C = 256;  m = ti - 160; }
    int tpc = C >> 6;
    int tr = m / tpc, tc = m % tpc;
#pragma unroll
    for (int i = 0; i < 4; ++i) {
      int lin = tid + i * 256;           // 0..1023
      int r = lin >> 4, c4 = (lin & 15) * 4;
      float4 f = *reinterpret_cast<const float4*>(
          src + (size_t)(tr * 64 + r) * C + tc * 64 + c4);
      tl[(c4 + 0) * 68 + r] = f2b(f.x);
      tl[(c4 + 1) * 68 + r] = f2b(f.y);
      tl[(c4 + 2) * 68 + r] = f2b(f.z);
      tl[(c4 + 3) * 68 + r] = f2b(f.w);
    }
    __syncthreads();
#pragma unroll
    for (int i = 0; i < 4; ++i) {
      int lin = tid + i * 256;
      int c = lin >> 4, r4 = (lin & 15) * 4;
      ushort4 u = *reinterpret_cast<const ushort4*>(&tl[c * 68 + r4]);
      *reinterpret_cast<ushort4*>(
          dst + (size_t)(tc * 64 + c) * R + tr * 64 + r4) = u;
    }
    return;
  }
  if (bx == 8416) {                      // kv bias concat
    bkv[tid] = bk[tid];
    bkv[256 + tid] = bv[tid];
    return;
  }
  {                                      // pad mask: one wave per (b,t) row
    int row = (bx - 8417) * 4 + wave;    // 0..615
    const float* tr = text + (size_t)row * CT_ + lane * 8;
    float4 f0 = *reinterpret_cast<const float4*>(tr);
    float4 f1 = *reinterpret_cast<const float4*>(tr + 4);
    float s = fabsf(f0.x) + fabsf(f0.y) + fabsf(f0.z) + fabsf(f0.w)
            + fabsf(f1.x) + fabsf(f1.y) + fabsf(f1.z) + fabsf(f1.w);
#pragma unroll
    for (int off = 1; off < 64; off <<= 1) s += __shfl_xor(s, off);
    if (lane == 0) padb[row] = (s <= 1e-6f) ? 1.0f : 0.0f;
  }
}

// ---- merged q-proj (blocks 0..511) + kv GEMM (blocks 512..591) ----------
__global__ __launch_bounds__(256) void qkv_kernel(
    const unsigned short* __restrict__ xb, const unsigned short* __restrict__ WqT,
    const float* __restrict__ bq, unsigned short* __restrict__ qout,
    const float* __restrict__ text, const unsigned short* __restrict__ WkvT,
    const float* __restrict__ bkv, float* __restrict__ kout,
    float* __restrict__ vout) {
  __shared__ unsigned short lA[4096];
  __shared__ unsigned short lB[4096];
  int tid = threadIdx.x;
  int lane = tid & 63, wave = tid >> 6;
  int l15 = lane & 15, quad = lane >> 4;
  if (blockIdx.x < 512) {
    // ---- q-proj: 128x128 tile, K=256, m97 async staging ----
    int bm = (blockIdx.x >> 1) * 128, bn = (blockIdx.x & 1) * 128;
    int wm = (wave & 1) * 64, wn = (wave >> 1) * 64;
    int crow = lane >> 2, ccol = (lane & 3) * 8;
    f32x4 acc[4][4] = {};
    for (int k0 = 0; k0 < 256; k0 += 32) {
#pragma unroll
      for (int ch = 0; ch < 2; ++ch) {
        int c = wave * 2 + ch;
        async_copy16(xb + (size_t)(bm + c * 16 + crow) * 256 + k0 + ccol,
                     &lA[c * 512]);
        async_copy16(WqT + (size_t)(bn + c * 16 + crow) * 256 + k0 + ccol,
                     &lB[c * 512]);
      }
      __syncthreads();
      bf16x8 af[4], bfr[4];
#pragma unroll
      for (int mi = 0; mi < 4; ++mi)
        af[mi] = *reinterpret_cast<const bf16x8*>(&lA[(wm + mi * 16 + l15) * 32 + quad * 8]);
#pragma unroll
      for (int ni = 0; ni < 4; ++ni)
        bfr[ni] = *reinterpret_cast<const bf16x8*>(&lB[(wn + ni * 16 + l15) * 32 + quad * 8]);
#pragma unroll
      for (int mi = 0; mi < 4; ++mi)
#pragma unroll
        for (int ni = 0; ni < 4; ++ni)
          acc[mi][ni] = __builtin_amdgcn_mfma_f32_16x16x32_bf16(af[mi], bfr[ni],
                                                                acc[mi][ni], 0, 0, 0);
      __syncthreads();
    }
#pragma unroll
    for (int mi = 0; mi < 4; ++mi) {
#pragma unroll
      for (int ni = 0; ni < 4; ++ni) {
        int gcol = bn + wn + ni * 16 + l15;
        float bsf = bq[gcol];
#pragma unroll
        for (int r = 0; r < 4; ++r) {
          int grow = bm + wm + mi * 16 + quad * 4 + r;
          qout[(size_t)grow * 256 + gcol] = f2b(acc[mi][ni][r] + bsf);
        }
      }
    }
  } else {
    // ---- kv: 64x64 tile over (616, 512), K=512, fp32 A pack ----
    int i = blockIdx.x - 512;
    int bm = (i % 10) * 64, bn = (i / 10) * 64;
    int srow = tid >> 2, sc8 = (tid & 3) * 8;
    int wm = (wave & 1) * 32, wn = (wave >> 1) * 32;
    f32x4 acc[2][2] = {};
    int gm = bm + srow, gn = bn + srow;
    const bool aok = (gm < BT_);
    for (int k0 = 0; k0 < CT_; k0 += 32) {
      uint4 apk = make_uint4(0, 0, 0, 0);
      if (aok) {
        const float* Af = text + (size_t)gm * CT_ + k0 + sc8;
        float4 f0 = *reinterpret_cast<const float4*>(Af);
        float4 f1 = *reinterpret_cast<const float4*>(Af + 4);
        apk.x = pack2(f0.x, f0.y); apk.y = pack2(f0.z, f0.w);
        apk.z = pack2(f1.x, f1.y); apk.w = pack2(f1.z, f1.w);
      }
      uint4 bpk = *reinterpret_cast<const uint4*>(WkvT + (size_t)gn * CT_ + k0 + sc8);
      *reinterpret_cast<uint4*>(&lA[srow * 40 + sc8]) = apk;
      *reinterpret_cast<uint4*>(&lB[srow * 40 + sc8]) = bpk;
      __syncthreads();
      bf16x8 a0 = *reinterpret_cast<const bf16x8*>(&lA[(wm + l15) * 40 + quad * 8]);
      bf16x8 a1 = *reinterpret_cast<const bf16x8*>(&lA[(wm + 16 + l15) * 40 + quad * 8]);
      bf16x8 b0 = *reinterpret_cast<const bf16x8*>(&lB[(wn + l15) * 40 + quad * 8]);
      bf16x8 b1 = *reinterpret_cast<const bf16x8*>(&lB[(wn + 16 + l15) * 40 + quad * 8]);
      acc[0][0] = __builtin_amdgcn_mfma_f32_16x16x32_bf16(a0, b0, acc[0][0], 0, 0, 0);
      acc[0][1] = __builtin_amdgcn_mfma_f32_16x16x32_bf16(a0, b1, acc[0][1], 0, 0, 0);
      acc[1][0] = __builtin_amdgcn_mfma_f32_16x16x32_bf16(a1, b0, acc[1][0], 0, 0, 0);
      acc[1][1] = __builtin_amdgcn_mfma_f32_16x16x32_bf16(a1, b1, acc[1][1], 0, 0, 0);
      __syncthreads();
    }
#pragma unroll
    for (int mt = 0; mt < 2; ++mt) {
#pragma unroll
      for (int nt = 0; nt < 2; ++nt) {
        int gcol = bn + wn + nt * 16 + l15;
        float bsf = bkv[gcol];
#pragma unroll
        for (int r = 0; r < 4; ++r) {
          int grow = bm + wm + mt * 16 + quad * 4 + r;
          if (grow >= BT_) continue;
          float v = acc[mt][nt][r] + bsf;
          if (gcol < 256) kout[(size_t)grow * 256 + gcol] = v;
          else            vout[(size_t)grow * 256 + gcol - 256] = v;
        }
      }
    }
  }
}

// ---- fused o-proj + residual + LN2 (64 rows/block, grid 512) ------------
__global__ __launch_bounds__(256) void gemm_oln(
    const unsigned short* __restrict__ A, const unsigned short* __restrict__ Bt,
    const float* __restrict__ bias, const unsigned short* __restrict__ xres,
    const float* __restrict__ alpha_ptr,
    const float* __restrict__ g2, const float* __restrict__ b2,
    unsigned short* __restrict__ ybf, float* __restrict__ yf32) {
  __shared__ unsigned short sm[16384];   // 32 KB: staging (10240) / yt (16384)
  unsigned short* lA = sm;               // 64x32 = 2048 shorts
  unsigned short* lB = sm + 2048;        // 256x32 = 8192 shorts
  unsigned short* yt = sm;               // 64x256 = 16384 shorts (aliased)
  const int K = 256;
  int tid = threadIdx.x;
  int bm = blockIdx.x * 64;
  int lane = tid & 63, wave = tid >> 6;
  int wm = (wave & 1) * 32, wn = (wave >> 1) * 128;
  int l15 = lane & 15, quad = lane >> 4;
  int crow = lane >> 2, ccol = (lane & 3) * 8;
  f32x4 acc[2][8] = {};
  for (int k0 = 0; k0 < K; k0 += 32) {
    async_copy16(A + (size_t)(bm + wave * 16 + crow) * K + k0 + ccol,
                 &lA[wave * 512]);
#pragma unroll
    for (int ch = wave; ch < 16; ch += 4)
      async_copy16(Bt + (size_t)(ch * 16 + crow) * K + k0 + ccol,
                   &lB[ch * 512]);
    __syncthreads();
    bf16x8 af[2], bfr[8];
#pragma unroll
    for (int mi = 0; mi < 2; ++mi)
      af[mi] = *reinterpret_cast<const bf16x8*>(&lA[(wm + mi * 16 + l15) * 32 + quad * 8]);
#pragma unroll
    for (int ni = 0; ni < 8; ++ni)
      bfr[ni] = *reinterpret_cast<const bf16x8*>(&lB[(wn + ni * 16 + l15) * 32 + quad * 8]);
#pragma unroll
    for (int mi = 0; mi < 2; ++mi)
#pragma unroll
      for (int ni = 0; ni < 8; ++ni)
        acc[mi][ni] = __builtin_amdgcn_mfma_f32_16x16x32_bf16(af[mi], bfr[ni],
                                                              acc[mi][ni], 0, 0, 0);
    __syncthreads();
  }
  float alpha = *alpha_ptr;
#pragma unroll
  for (int mi = 0; mi < 2; ++mi) {
#pragma unroll
    for (int ni = 0; ni < 8; ++ni) {
      int gcol = wn + ni * 16 + l15;
      float bsf = bias[gcol];
#pragma unroll
      for (int r = 0; r < 4; ++r) {
        int lrow = wm + mi * 16 + quad * 4 + r;
        float v = acc[mi][ni][r] + bsf;
        float y0 = bf2f(xres[(size_t)(bm + lrow) * 256 + gcol]) + alpha * v;
        yt[lrow * 256 + gcol] = f2b(y0);
      }
    }
  }
  __syncthreads();
  for (int it = 0; it < 16; ++it) {
    int row = wave * 16 + it;
    ushort4 u = *reinterpret_cast<const ushort4*>(&yt[row * 256 + lane * 4]);
    float v0 = bf2f(u.x), v1 = bf2f(u.y), v2 = bf2f(u.z), v3 = bf2f(u.w);
    float s = v0 + v1 + v2 + v3;
    float q = v0 * v0 + v1 * v1 + v2 * v2 + v3 * v3;
#pragma unroll
    for (int off = 1; off < 64; off <<= 1) {
      s += __shfl_xor(s, off);
      q += __shfl_xor(q, off);
    }
    float mean = s * (1.0f / 256.0f);
    float var  = q * (1.0f / 256.0f) - mean * mean;
    float rstd = rsqrtf(var + 1e-5f);
    float4 gv = *reinterpret_cast<const float4*>(g2 + lane * 4);
    float4 bv = *reinterpret_cast<const float4*>(b2 + lane * 4);
    float o0 = (v0 - mean) * rstd * gv.x + bv.x;
    float o1 = (v1 - mean) * rstd * gv.y + bv.y;
    float o2 = (v2 - mean) * rstd * gv.z + bv.z;
    float o3 = (v3 - mean) * rstd * gv.w + bv.w;
    size_t base = (size_t)(bm + row) * 256 + lane * 4;
    ushort4 ob;
    ob.x = f2b(o0); ob.y = f2b(o1); ob.z = f2b(o2); ob.w = f2b(o3);
    *reinterpret_cast<ushort4*>(ybf + base) = ob;
    *reinterpret_cast<float4*>(yf32 + base) = make_float4(o0, o1, o2, o3);
  }
}

// ---------- attention v3: MFMA QK^T + packed-index top-5 ------------------
#define SSTR 83
#define VSTR 33
#define NEGBIG -3.0e38f
__device__ __forceinline__ void ins5(float sv, float& tv0, float& tv1,
                                     float& tv2, float& tv3, float& tv4) {
  bool g0 = sv > tv0, g1 = sv > tv1, g2 = sv > tv2, g3 = sv > tv3, g4 = sv > tv4;
  tv4 = g4 ? (g3 ? tv3 : sv) : tv4;
  tv3 = g3 ? (g2 ? tv2 : sv) : tv3;
  tv2 = g2 ? (g1 ? tv1 : sv) : tv2;
  tv1 = g1 ? (g0 ? tv0 : sv) : tv1;
  tv0 = g0 ? sv : tv0;
}
__global__ __launch_bounds__(256) void attn_kernel(
    unsigned short* qa, const float* __restrict__ k,
    const float* __restrict__ v, const float* __restrict__ padb,
    const float* __restrict__ ls_ptr) {
  __shared__ unsigned short qb[64 * 40];
  __shared__ unsigned short kb[80 * 40];
  __shared__ float S[64 * SSTR];
  __shared__ float vs[TT * VSTR];
  __shared__ float rn[64];
  __shared__ float scs[80];
  __shared__ int allpad_s;
  int tid = threadIdx.x;
  int h = blockIdx.y, b = blockIdx.z;
  size_t qbase = ((size_t)b * NPIX + blockIdx.x * 64) * CV_ + h * DH_;
  size_t kvbase = (size_t)b * TT * CV_ + h * DH_;
  float ls = *ls_ptr;
  ls = fminf(fmaxf(ls, -2.0f), 2.0f);
  float scale = expf(ls) * 0.17677669529663687f;
  if (tid == 0) allpad_s = 1;
  __syncthreads();
  int qrow = tid >> 2, qq = tid & 3;
  uint4 qv4 = *reinterpret_cast<const uint4*>(qa + qbase + (size_t)qrow * CV_ + qq * 8);
  *reinterpret_cast<uint4*>(&qb[qrow * 40 + qq * 8]) = qv4;
  {
    float ssq = 0.f;
    unsigned w[4] = {qv4.x, qv4.y, qv4.z, qv4.w};
#pragma unroll
    for (int i = 0; i < 4; ++i) {
      float a = bf2f((unsigned short)(w[i] & 0xFFFF));
      float bb = bf2f((unsigned short)(w[i] >> 16));
      ssq += a * a + bb * bb;
    }
    ssq += __shfl_xor(ssq, 1);
    ssq += __shfl_xor(ssq, 2);
    if (qq == 0) rn[qrow] = scale / fmaxf(sqrtf(ssq), 1e-6f);
  }
  if (tid < 154) {
    int kr = tid >> 1, kh = tid & 1;
    const float* kp = k + kvbase + (size_t)kr * CV_ + kh * 16;
    float4 f0 = *reinterpret_cast<const float4*>(kp);
    float4 f1 = *reinterpret_cast<const float4*>(kp + 4);
    float4 f2 = *reinterpret_cast<const float4*>(kp + 8);
    float4 f3 = *reinterpret_cast<const float4*>(kp + 12);
    float ks2 = f0.x*f0.x + f0.y*f0.y + f0.z*f0.z + f0.w*f0.w
              + f1.x*f1.x + f1.y*f1.y + f1.z*f1.z + f1.w*f1.w
              + f2.x*f2.x + f2.y*f2.y + f2.z*f2.z + f2.w*f2.w
              + f3.x*f3.x + f3.y*f3.y + f3.z*f3.z + f3.w*f3.w;
    uint4 p0, p1;
    p0.x = pack2(f0.x, f0.y); p0.y = pack2(f0.z, f0.w);
    p0.z = pack2(f1.x, f1.y); p0.w = pack2(f1.z, f1.w);
    p1.x = pack2(f2.x, f2.y); p1.y = pack2(f2.z, f2.w);
    p1.z = pack2(f3.x, f3.y); p1.w = pack2(f3.z, f3.w);
    *reinterpret_cast<uint4*>(&kb[kr * 40 + kh * 16]) = p0;
    *reinterpret_cast<uint4*>(&kb[kr * 40 + kh * 16 + 8]) = p1;
    ks2 += __shfl_xor(ks2, 1);
    if (kh == 0) {
      float p = padb[b * TT + kr];
      float sc = (p == 0.0f) ? 1.0f / fmaxf(sqrtf(ks2), 1e-6f) : 0.0f;
      scs[kr] = sc;
      if (sc > 0.0f) allpad_s = 0;
    }
  } else if (tid < 157) {
    scs[77 + (tid - 154)] = 0.0f;
  } else if (tid >= 160 && tid < 172) {
    int i = tid - 160;
    *reinterpret_cast<uint4*>(&kb[(77 + (i >> 2)) * 40 + (i & 3) * 8]) =
        make_uint4(0, 0, 0, 0);
  }
  for (int j = tid; j < TT * 8; j += 256) {
    int t = j >> 3, d4 = j & 7;
    float4 f = *reinterpret_cast<const float4*>(
        v + kvbase + (size_t)t * CV_ + d4 * 4);
    float* vp = &vs[t * VSTR + d4 * 4];
    vp[0] = f.x; vp[1] = f.y; vp[2] = f.z; vp[3] = f.w;
  }
  __syncthreads();
  {
    int lane = tid & 63, wave = tid >> 6;
    int wm = wave * 16;
    int l15 = lane & 15, quad = lane >> 4;
    f32x4 acc[5] = {};
    bf16x8 af = *reinterpret_cast<const bf16x8*>(&qb[(wm + l15) * 40 + quad * 8]);
    bf16x8 bfr[5];
#pragma unroll
    for (int ni = 0; ni < 5; ++ni)
      bfr[ni] = *reinterpret_cast<const bf16x8*>(&kb[(ni * 16 + l15) * 40 + quad * 8]);
#pragma unroll
    for (int ni = 0; ni < 5; ++ni)
      acc[ni] = __builtin_amdgcn_mfma_f32_16x16x32_bf16(af, bfr[ni], acc[ni], 0, 0, 0);
#pragma unroll
    for (int ni = 0; ni < 5; ++ni) {
      int col = ni * 16 + l15;
      float sc = scs[col];
#pragma unroll
      for (int r = 0; r < 4; ++r) {
        int row = wm + quad * 4 + r;
        float val = (sc > 0.0f) ? acc[ni][r] * rn[row] * sc : NEGBIG;
        unsigned pb = (__float_as_uint(val) & 0xFFFFFF80u) | (unsigned)col;
        S[row * SSTR + col] = __uint_as_float(pb);
      }
    }
  }
  __syncthreads();
  int allpad = allpad_s;
  int row = qrow;
  const float* Srow = &S[row * SSTR];
  int t0 = qq * 20, t1 = (qq == 3) ? TT : t0 + 20;
  float tv0 = -INFINITY, tv1 = -INFINITY, tv2 = -INFINITY,
        tv3 = -INFINITY, tv4 = -INFINITY;
  for (int t = t0; t < t1; ++t)
    ins5(Srow[t], tv0, tv1, tv2, tv3, tv4);
#pragma unroll
  for (int m = 1; m <= 2; m <<= 1) {
    float n0 = __shfl_xor(tv0, m), n1 = __shfl_xor(tv1, m),
          n2 = __shfl_xor(tv2, m), n3 = __shfl_xor(tv3, m),
          n4 = __shfl_xor(tv4, m);
    ins5(n0, tv0, tv1, tv2, tv3, tv4);
    ins5(n1, tv0, tv1, tv2, tv3, tv4);
    ins5(n2, tv0, tv1, tv2, tv3, tv4);
    ins5(n3, tv0, tv1, tv2, tv3, tv4);
    ins5(n4, tv0, tv1, tv2, tv3, tv4);
  }
  float o[8];
#pragma unroll
  for (int d = 0; d < 8; ++d) o[d] = 0.f;
  if (!allpad) {
    float e0 = 1.0f;
    float e1 = expf(tv1 - tv0);
    float e2 = expf(tv2 - tv0);
    float e3 = expf(tv3 - tv0);
    float e4 = expf(tv4 - tv0);
    float inv = 1.0f / (e0 + e1 + e2 + e3 + e4);
    int i0 = __float_as_uint(tv0) & 0x7F, i1 = __float_as_uint(tv1) & 0x7F,
        i2 = __float_as_uint(tv2) & 0x7F, i3 = __float_as_uint(tv3) & 0x7F,
        i4 = __float_as_uint(tv4) & 0x7F;
    const float* v0p = &vs[i0 * VSTR + qq * 8];
    const float* v1p = &vs[i1 * VSTR + qq * 8];
    const float* v2p = &vs[i2 * VSTR + qq * 8];
    const float* v3p = &vs[i3 * VSTR + qq * 8];
    const float* v4p = &vs[i4 * VSTR + qq * 8];
#pragma unroll
    for (int d = 0; d < 8; ++d)
      o[d] = (e0 * v0p[d] + e1 * v1p[d] + e2 * v2p[d] + e3 * v3p[d] + e4 * v4p[d]) * inv;
  }
  unsigned short* qp = qa + qbase + (size_t)row * CV_ + qq * 8;
  uint4 ou;
  ou.x = ((unsigned)f2b(o[1]) << 16) | f2b(o[0]);
  ou.y = ((unsigned)f2b(o[3]) << 16) | f2b(o[2]);
  ou.z = ((unsigned)f2b(o[5]) << 16) | f2b(o[4]);
  ou.w = ((unsigned)f2b(o[7]) << 16) | f2b(o[6]);
  *reinterpret_cast<uint4*>(qp) = ou;
}

// ---------- fused FFN: out = y + gelu(y@W1+b1)@W2 + b2 -------------------
// R3/R5-proven loop: 256 blocks, 128 rows, 512 threads (8 waves, 2/SIMD).
// 64 uniform 16KB stage-steps, double-buffered Wb (2x16KB), counted
// vmcnt(2), 2 raw s_barriers/step, T2 swizzle (slot(2b) ^= (row>>1)&3),
// setprio around MFMA. p=0..3 W1 (phase1), p=4..7 W2 (phase2).
// R8 delta: stage addressing strength-reduced to two running pointers
// (w1p += 64/step, +32512 at chunk rollover; w2p += 32/step); the two
// wasted wrap-around stages are skipped; final step waits vmcnt(0)
// (only stage 63 outstanding there). Data/order bit-identical to R5.
#define XSTR 264   // y-tile stride (2-way-free reads)
#define HSTR 136   // H stride (2-way-free reads)
__global__ __launch_bounds__(512) void ffn_fused(
    const unsigned short* __restrict__ ybf, const unsigned short* __restrict__ W1T,
    const float* __restrict__ b1f, const unsigned short* __restrict__ W2T,
    const float* __restrict__ b2f, float* __restrict__ yio) {
  __shared__ unsigned short xs[128 * XSTR];  // 67584 B
  __shared__ unsigned short Hs[128 * HSTR];  // 34816 B
  __shared__ unsigned short Wb[16384];       // 32 KB = 2 x 16KB halves
  int tid = threadIdx.x, lane = tid & 63, wave = tid >> 6;  // wave 0..7
  int l15 = lane & 15, quad = lane >> 4;
  int crow = lane >> 2;
  // T2 swizzle: slot(2b) ^= (row>>1)&3. write side: row=crow -> (lane>>3)&3
  int ccs = (((lane & 3) ^ ((lane >> 3) & 3)) * 8);  // pre-swizzled global col
  int rsw = ((quad ^ ((l15 >> 1) & 3)) * 8);         // swizzled LDS read col
  int bm = blockIdx.x * 128;
  {  // stage y-tile (padded stride -> VGPR path); 64 shorts per thread
    int row = tid >> 2, kh = (tid & 3) * 64;
    const unsigned short* src = ybf + (size_t)(bm + row) * 256 + kh;
    unsigned short* dst = &xs[row * XSTR + kh];
#pragma unroll
    for (int i = 0; i < 8; ++i)
      *reinterpret_cast<uint4*>(dst + i * 8) =
          *reinterpret_cast<const uint4*>(src + i * 8);
  }
  int wm2 = (wave & 1) * 64, wn2 = (wave >> 1) * 64;   // phase2 tile
  int wh1 = (wave & 1) * 64, wr1 = (wave >> 1) * 32;   // phase1 tile
  // Running stage pointers (strength-reduced; verified vs R5 formulas):
  // W1 step (chunk c, p): W1T + (c*128 + wave*16 + crow)*256 + p*64 + sl*32 + ccs
  // W2 step (chunk c, q): W2T + ((wave*2+i)*16 + crow)*1024 + c*128 + q*32 + ccs
  const unsigned short* w1p = W1T + (size_t)(wave * 16 + crow) * 256 + ccs;
  const unsigned short* w2p = W2T + (size_t)(wave * 32 + crow) * 1024 + ccs;
  // stage one 16KB step of compile-time kind p2 into Wb half `half`
  auto stage_step = [&](int p2, int half) {
    unsigned short* buf = &Wb[half * 8192];
    if (p2 < 4) {
      async_copy16(w1p,      &buf[wave * 512]);
      async_copy16(w1p + 32, &buf[4096 + wave * 512]);
      w1p += 64;
      if (p2 == 3) w1p += 32512;         // next chunk: +32768 total
    } else {
      async_copy16(w2p,          &buf[wave * 1024]);
      async_copy16(w2p + 16384,  &buf[wave * 1024 + 512]);
      w2p += 32;                          // 4 steps = +128 = chunk stride
    }
  };
  f32x4 acc[4][4] = {};
  stage_step(0, 0); stage_step(1, 1);
  for (int c = 0; c < 8; ++c) {
    f32x4 acc1[4][2] = {};
#pragma unroll
    for (int p = 0; p < 8; ++p) {
      // ledger: outstanding = {st:2, st+1:2} (st=c*8+p) except final step
      // (st=63: only {63:2}); vmcnt(2)/vmcnt(0) drains step st.
      if (p == 7 && c == 7)
        asm volatile("s_waitcnt vmcnt(0) lgkmcnt(0)" ::: "memory");
      else
        asm volatile("s_waitcnt vmcnt(2) lgkmcnt(0)" ::: "memory");
      __builtin_amdgcn_s_barrier();
      __builtin_amdgcn_sched_barrier(0);
      const unsigned short* buf = &Wb[(p & 1) * 8192];
      if (p < 4) {
#pragma unroll
        for (int sl = 0; sl < 2; ++sl) {
          int k = p * 64 + sl * 32;
          bf16x8 af[4], bfr[2];
#pragma unroll
          for (int mi = 0; mi < 4; ++mi)
            af[mi] = *reinterpret_cast<const bf16x8*>(
                &buf[sl * 4096 + (wh1 + mi * 16 + l15) * 32 + rsw]);
#pragma unroll
          for (int ni = 0; ni < 2; ++ni)
            bfr[ni] = *reinterpret_cast<const bf16x8*>(
                &xs[(wr1 + ni * 16 + l15) * XSTR + k + quad * 8]);
          __builtin_amdgcn_s_setprio(1);
#pragma unroll
          for (int mi = 0; mi < 4; ++mi)
#pragma unroll
            for (int ni = 0; ni < 2; ++ni)
              acc1[mi][ni] = __builtin_amdgcn_mfma_f32_16x16x32_bf16(
                  af[mi], bfr[ni], acc1[mi][ni], 0, 0, 0);
          __builtin_amdgcn_s_setprio(0);
        }
        if (p == 3) {   // GELU + bias -> Hs (phase1 of chunk c complete)
#pragma unroll
          for (int mi = 0; mi < 4; ++mi) {
            int hb = wh1 + mi * 16 + quad * 4;
            float b0 = b1f[c * 128 + hb],      b1v = b1f[c * 128 + hb + 1];
            float b2v = b1f[c * 128 + hb + 2], b3 = b1f[c * 128 + hb + 3];
#pragma unroll
            for (int ni = 0; ni < 2; ++ni) {
              int row = wr1 + ni * 16 + l15;
              ushort4 hw;
              hw.x = f2b(gelu_t(acc1[mi][ni][0] + b0));
              hw.y = f2b(gelu_t(acc1[mi][ni][1] + b1v));
              hw.z = f2b(gelu_t(acc1[mi][ni][2] + b2v));
              hw.w = f2b(gelu_t(acc1[mi][ni][3] + b3));
              *reinterpret_cast<ushort4*>(&Hs[row * HSTR + hb]) = hw;
            }
          }
        }
      } else {
        int kk = (p - 4) * 32;
        bf16x8 af[4], bfr[4];
#pragma unroll
        for (int mi = 0; mi < 4; ++mi)
          af[mi] = *reinterpret_cast<const bf16x8*>(
              &Hs[(wm2 + mi * 16 + l15) * HSTR + kk + quad * 8]);
#pragma unroll
        for (int ni = 0; ni < 4; ++ni)
          bfr[ni] = *reinterpret_cast<const bf16x8*>(
              &buf[(wn2 + ni * 16 + l15) * 32 + rsw]);
        __builtin_amdgcn_s_setprio(1);
#pragma unroll
        for (int mi = 0; mi < 4; ++mi)
#pragma unroll
          for (int ni = 0; ni < 4; ++ni)
            acc[mi][ni] = __builtin_amdgcn_mfma_f32_16x16x32_bf16(
                af[mi], bfr[ni], acc[mi][ni], 0, 0, 0);
        __builtin_amdgcn_s_setprio(0);
      }
      __builtin_amdgcn_sched_barrier(0);
      __builtin_amdgcn_s_barrier();
      __builtin_amdgcn_sched_barrier(0);
      // issue stage st+2 (skip past the end; kinds are compile-time)
      if (c < 7 || p < 6)
        stage_step((p + 2) & 7, p & 1);
    }
  }
  // ---- epilogue: out = resid + acc + b2 (fp32 RMW, thread-owned) ----
#pragma unroll
  for (int mi = 0; mi < 4; ++mi)
#pragma unroll
    for (int ni = 0; ni < 4; ++ni) {
      int col = wn2 + ni * 16 + l15;
      float bs = b2f[col];
#pragma unroll
      for (int r = 0; r < 4; ++r) {
        int g = bm + wm2 + mi * 16 + quad * 4 + r;
        size_t oi = (size_t)g * 256 + col;
        yio[oi] = yio[oi] + acc[mi][ni][r] + bs;
      }
    }
}

extern "C" void kernel_launch(void* const* d_in, const int* in_sizes, int n_in,
                              void* d_out, int out_size, void* d_ws, size_t ws_size,
                              hipStream_t stream) {
  const float* visual = (const float*)d_in[0];
  const float* text   = (const float*)d_in[1];
  const float* Wq  = (const float*)d_in[2];
  const float* bq  = (const float*)d_in[3];
  const float* Wk  = (const float*)d_in[4];
  const float* bk  = (const float*)d_in[5];
  const float* Wv  = (const float*)d_in[6];
  const float* bv  = (const float*)d_in[7];
  const float* Wo  = (const float*)d_in[8];
  const float* bo  = (const float*)d_in[9];
  const float* g1  = (const float*)d_in[10];
  const float* b1  = (const float*)d_in[11];
  const float* g2  = (const float*)d_in[12];
  const float* b2  = (const float*)d_in[13];
  const float* W1  = (const float*)d_in[14];
  const float* bf1 = (const float*)d_in[15];
  const float* W2  = (const float*)d_in[16];
  const float* bff2 = (const float*)d_in[17];
  const float* lsc = (const float*)d_in[18];
  const float* alp = (const float*)d_in[19];

  char* ws = (char*)d_ws;
  size_t off = 0;
  auto alloc = [&](size_t bytes) -> char* {
    char* p = ws + off;
    off += (bytes + 255) & ~(size_t)255;
    return p;
  };
  unsigned short* WqT = (unsigned short*)alloc((size_t)65536 * 2);
  unsigned short* WkT = (unsigned short*)alloc((size_t)131072 * 2);  // contiguous
  unsigned short* WvT = (unsigned short*)alloc((size_t)131072 * 2);  // with WkT
  unsigned short* WoT = (unsigned short*)alloc((size_t)65536 * 2);
  unsigned short* W1T = (unsigned short*)alloc((size_t)262144 * 2);
  unsigned short* W2T = (unsigned short*)alloc((size_t)262144 * 2);
  float*          bkv  = (float*)alloc(512 * 4);
  float*          kbuf = (float*)alloc((size_t)BT_ * CV_ * 4);
  float*          vbuf = (float*)alloc((size_t)BT_ * CV_ * 4);
  float*          padb = (float*)alloc((size_t)BT_ * 4);
  char* U = ws + off;                      // total ws ~= 36.3 MB
  unsigned short* xbuf = (unsigned short*)U;
  unsigned short* qbuf = (unsigned short*)(U + 16777216);
  float*          ybuf = (float*)d_out;

  // 1. prep: LN1 + LDS-tiled weight convT + kv bias + pad mask
  prep_kernel<<<8571, 256, 0, stream>>>(visual, g1, b1, xbuf,
                                        Wq, Wk, Wv, Wo, W1, W2,
                                        WqT, WkT, WvT, WoT, W1T, W2T,
                                        bk, bv, bkv, text, padb);
  // 2. q-proj + kv GEMM merged
  qkv_kernel<<<592, 256, 0, stream>>>(xbuf, WqT, bq, qbuf,
                                      text, WkT, bkv, kbuf, vbuf);
  // 3. attention v3: qbuf -> qbuf in place
  attn_kernel<<<dim3(64, NH_, NB), 256, 0, stream>>>(qbuf, kbuf, vbuf, padb, lsc);
  // 4. fused o-proj + residual + LN2: y bf16 (xbuf) + y fp32 (d_out)
  gemm_oln<<<512, 256, 0, stream>>>(qbuf, WoT, bo, xbuf, alp, g2, b2,
                                    xbuf, ybuf);
  // 5. fused FFN (reads y bf16 + y fp32 resid, writes d_out fp32 in place)
  ffn_fused<<<256, 512, 0, stream>>>(xbuf, W1T, bf1, W2T, bff2, ybuf);
}

// Round 9
// 280.446 us; speedup vs baseline: 1.0179x; 1.0179x over previous
//
#include <hip/hip_runtime.h>
#include <math.h>

// Problem constants
#define NB   8
#define NPIX 4096          // H*W
#define MROW 32768         // B*H*W
#define CV_  256
#define TT   77
#define CT_  512
#define NH_  8
#define DH_  32
#define BT_  616           // B*T

typedef __bf16 bf16x8 __attribute__((ext_vector_type(8)));
typedef float  f32x4  __attribute__((ext_vector_type(4)));

__device__ __forceinline__ float bf2f(unsigned short u) {
  return __uint_as_float(((unsigned)u) << 16);
}
__device__ __forceinline__ unsigned short f2b(float f) {
  unsigned u = __float_as_uint(f);
  return (unsigned short)((u + 0x7FFFu + ((u >> 16) & 1u)) >> 16);
}
__device__ __forceinline__ unsigned pack2(float lo, float hi) {
  return ((unsigned)f2b(hi) << 16) | (unsigned)f2b(lo);
}
__device__ __forceinline__ void async_copy16(const unsigned short* g,
                                             unsigned short* l) {
  __builtin_amdgcn_global_load_lds(
      (const __attribute__((address_space(1))) void*)g,
      (__attribute__((address_space(3))) void*)l, 16, 0, 0);
}
// tanh-GELU: 0.5*v*(1+tanh(0.79788456*(v+0.044715 v^3))) = v - v/(e^{2u}+1)
__device__ __forceinline__ float gelu_t(float v) {
  float p = v * fmaf(0.0713548162726f, v * v, 1.59576912161f);
  float e = __expf(p);
  return v - v / (e + 1.0f);
}

// -- prep: LN1 (0..8191) + LDS-tiled weight convT (8192..8415) +
//          kv bias (8416) + pad mask (8417..8570) --------------------------
__global__ __launch_bounds__(256) void prep_kernel(
    const float* __restrict__ visual, const float* __restrict__ g1,
    const float* __restrict__ b1, unsigned short* __restrict__ xbuf,
    const float* __restrict__ s0, const float* __restrict__ s1,
    const float* __restrict__ s2, const float* __restrict__ s3,
    const float* __restrict__ s4, const float* __restrict__ s5,
    unsigned short* __restrict__ d0, unsigned short* __restrict__ d1,
    unsigned short* __restrict__ d2, unsigned short* __restrict__ d3,
    unsigned short* __restrict__ d4, unsigned short* __restrict__ d5,
    const float* __restrict__ bk, const float* __restrict__ bv,
    float* __restrict__ bkv, const float* __restrict__ text,
    float* __restrict__ padb) {
  __shared__ unsigned short tl[64 * 68];   // 8704 B transpose tile
  int bx = blockIdx.x;
  int tid = threadIdx.x;
  int wave = tid >> 6, lane = tid & 63;
  if (bx < 8192) {                       // LN1: visual fp32 -> x bf16
    int row = bx * 4 + wave;
    size_t base = (size_t)row * 256 + lane * 4;
    float4 f = *reinterpret_cast<const float4*>(visual + base);
    float v0 = f.x, v1 = f.y, v2 = f.z, v3 = f.w;
    float s = v0 + v1 + v2 + v3;
    float q = v0 * v0 + v1 * v1 + v2 * v2 + v3 * v3;
#pragma unroll
    for (int off = 1; off < 64; off <<= 1) {
      s += __shfl_xor(s, off);
      q += __shfl_xor(q, off);
    }
    float mean = s * (1.0f / 256.0f);
    float var  = q * (1.0f / 256.0f) - mean * mean;
    float rstd = rsqrtf(var + 1e-5f);
    float4 gv = *reinterpret_cast<const float4*>(g1 + lane * 4);
    float4 bv4 = *reinterpret_cast<const float4*>(b1 + lane * 4);
    ushort4 o;
    o.x = f2b((v0 - mean) * rstd * gv.x + bv4.x);
    o.y = f2b((v1 - mean) * rstd * gv.y + bv4.y);
    o.z = f2b((v2 - mean) * rstd * gv.z + bv4.z);
    o.w = f2b((v3 - mean) * rstd * gv.w + bv4.w);
    *reinterpret_cast<ushort4*>(xbuf + base) = o;
    return;
  }
  if (bx < 8416) {                       // LDS-tiled 64x64 transpose
    int ti = bx - 8192;                  // 0..223
    const float* src; unsigned short* dst; int R, C, m;
    if      (ti < 16)  { src = s0; dst = d0; R = 256;  C = 256;  m = ti; }
    else if (ti < 48)  { src = s1; dst = d1; R = 512;  C = 256;  m = ti - 16; }
    else if (ti < 80)  { src = s2; dst = d2; R = 512;  C = 256;  m = ti - 48; }
    else if (ti < 96)  { src = s3; dst = d3; R = 256;  C = 256;  m = ti - 80; }
    else if (ti < 160) { src = s4; dst = d4; R = 256;  C = 1024; m = ti - 96; }
    else               { src = s5; dst = d5; R = 1024; C = 256;  m = ti - 160; }
    int tpc = C >> 6;
    int tr = m / tpc, tc = m % tpc;
#pragma unroll
    for (int i = 0; i < 4; ++i) {
      int lin = tid + i * 256;           // 0..1023
      int r = lin >> 4, c4 = (lin & 15) * 4;
      float4 f = *reinterpret_cast<const float4*>(
          src + (size_t)(tr * 64 + r) * C + tc * 64 + c4);
      tl[(c4 + 0) * 68 + r] = f2b(f.x);
      tl[(c4 + 1) * 68 + r] = f2b(f.y);
      tl[(c4 + 2) * 68 + r] = f2b(f.z);
      tl[(c4 + 3) * 68 + r] = f2b(f.w);
    }
    __syncthreads();
#pragma unroll
    for (int i = 0; i < 4; ++i) {
      int lin = tid + i * 256;
      int c = lin >> 4, r4 = (lin & 15) * 4;
      ushort4 u = *reinterpret_cast<const ushort4*>(&tl[c * 68 + r4]);
      *reinterpret_cast<ushort4*>(
          dst + (size_t)(tc * 64 + c) * R + tr * 64 + r4) = u;
    }
    return;
  }
  if (bx == 8416) {                      // kv bias concat
    bkv[tid] = bk[tid];
    bkv[256 + tid] = bv[tid];
    return;
  }
  {                                      // pad mask: one wave per (b,t) row
    int row = (bx - 8417) * 4 + wave;    // 0..615
    const float* tr = text + (size_t)row * CT_ + lane * 8;
    float4 f0 = *reinterpret_cast<const float4*>(tr);
    float4 f1 = *reinterpret_cast<const float4*>(tr + 4);
    float s = fabsf(f0.x) + fabsf(f0.y) + fabsf(f0.z) + fabsf(f0.w)
            + fabsf(f1.x) + fabsf(f1.y) + fabsf(f1.z) + fabsf(f1.w);
#pragma unroll
    for (int off = 1; off < 64; off <<= 1) s += __shfl_xor(s, off);
    if (lane == 0) padb[row] = (s <= 1e-6f) ? 1.0f : 0.0f;
  }
}

// ---- merged q-proj (blocks 0..511) + kv GEMM (blocks 512..591) ----------
__global__ __launch_bounds__(256) void qkv_kernel(
    const unsigned short* __restrict__ xb, const unsigned short* __restrict__ WqT,
    const float* __restrict__ bq, unsigned short* __restrict__ qout,
    const float* __restrict__ text, const unsigned short* __restrict__ WkvT,
    const float* __restrict__ bkv, float* __restrict__ kout,
    float* __restrict__ vout) {
  __shared__ unsigned short lA[4096];
  __shared__ unsigned short lB[4096];
  int tid = threadIdx.x;
  int lane = tid & 63, wave = tid >> 6;
  int l15 = lane & 15, quad = lane >> 4;
  if (blockIdx.x < 512) {
    // ---- q-proj: 128x128 tile, K=256, m97 async staging ----
    int bm = (blockIdx.x >> 1) * 128, bn = (blockIdx.x & 1) * 128;
    int wm = (wave & 1) * 64, wn = (wave >> 1) * 64;
    int crow = lane >> 2, ccol = (lane & 3) * 8;
    f32x4 acc[4][4] = {};
    for (int k0 = 0; k0 < 256; k0 += 32) {
#pragma unroll
      for (int ch = 0; ch < 2; ++ch) {
        int c = wave * 2 + ch;
        async_copy16(xb + (size_t)(bm + c * 16 + crow) * 256 + k0 + ccol,
                     &lA[c * 512]);
        async_copy16(WqT + (size_t)(bn + c * 16 + crow) * 256 + k0 + ccol,
                     &lB[c * 512]);
      }
      __syncthreads();
      bf16x8 af[4], bfr[4];
#pragma unroll
      for (int mi = 0; mi < 4; ++mi)
        af[mi] = *reinterpret_cast<const bf16x8*>(&lA[(wm + mi * 16 + l15) * 32 + quad * 8]);
#pragma unroll
      for (int ni = 0; ni < 4; ++ni)
        bfr[ni] = *reinterpret_cast<const bf16x8*>(&lB[(wn + ni * 16 + l15) * 32 + quad * 8]);
#pragma unroll
      for (int mi = 0; mi < 4; ++mi)
#pragma unroll
        for (int ni = 0; ni < 4; ++ni)
          acc[mi][ni] = __builtin_amdgcn_mfma_f32_16x16x32_bf16(af[mi], bfr[ni],
                                                                acc[mi][ni], 0, 0, 0);
      __syncthreads();
    }
#pragma unroll
    for (int mi = 0; mi < 4; ++mi) {
#pragma unroll
      for (int ni = 0; ni < 4; ++ni) {
        int gcol = bn + wn + ni * 16 + l15;
        float bsf = bq[gcol];
#pragma unroll
        for (int r = 0; r < 4; ++r) {
          int grow = bm + wm + mi * 16 + quad * 4 + r;
          qout[(size_t)grow * 256 + gcol] = f2b(acc[mi][ni][r] + bsf);
        }
      }
    }
  } else {
    // ---- kv: 64x64 tile over (616, 512), K=512, fp32 A pack ----
    int i = blockIdx.x - 512;
    int bm = (i % 10) * 64, bn = (i / 10) * 64;
    int srow = tid >> 2, sc8 = (tid & 3) * 8;
    int wm = (wave & 1) * 32, wn = (wave >> 1) * 32;
    f32x4 acc[2][2] = {};
    int gm = bm + srow, gn = bn + srow;
    const bool aok = (gm < BT_);
    for (int k0 = 0; k0 < CT_; k0 += 32) {
      uint4 apk = make_uint4(0, 0, 0, 0);
      if (aok) {
        const float* Af = text + (size_t)gm * CT_ + k0 + sc8;
        float4 f0 = *reinterpret_cast<const float4*>(Af);
        float4 f1 = *reinterpret_cast<const float4*>(Af + 4);
        apk.x = pack2(f0.x, f0.y); apk.y = pack2(f0.z, f0.w);
        apk.z = pack2(f1.x, f1.y); apk.w = pack2(f1.z, f1.w);
      }
      uint4 bpk = *reinterpret_cast<const uint4*>(WkvT + (size_t)gn * CT_ + k0 + sc8);
      *reinterpret_cast<uint4*>(&lA[srow * 40 + sc8]) = apk;
      *reinterpret_cast<uint4*>(&lB[srow * 40 + sc8]) = bpk;
      __syncthreads();
      bf16x8 a0 = *reinterpret_cast<const bf16x8*>(&lA[(wm + l15) * 40 + quad * 8]);
      bf16x8 a1 = *reinterpret_cast<const bf16x8*>(&lA[(wm + 16 + l15) * 40 + quad * 8]);
      bf16x8 b0 = *reinterpret_cast<const bf16x8*>(&lB[(wn + l15) * 40 + quad * 8]);
      bf16x8 b1 = *reinterpret_cast<const bf16x8*>(&lB[(wn + 16 + l15) * 40 + quad * 8]);
      acc[0][0] = __builtin_amdgcn_mfma_f32_16x16x32_bf16(a0, b0, acc[0][0], 0, 0, 0);
      acc[0][1] = __builtin_amdgcn_mfma_f32_16x16x32_bf16(a0, b1, acc[0][1], 0, 0, 0);
      acc[1][0] = __builtin_amdgcn_mfma_f32_16x16x32_bf16(a1, b0, acc[1][0], 0, 0, 0);
      acc[1][1] = __builtin_amdgcn_mfma_f32_16x16x32_bf16(a1, b1, acc[1][1], 0, 0, 0);
      __syncthreads();
    }
#pragma unroll
    for (int mt = 0; mt < 2; ++mt) {
#pragma unroll
      for (int nt = 0; nt < 2; ++nt) {
        int gcol = bn + wn + nt * 16 + l15;
        float bsf = bkv[gcol];
#pragma unroll
        for (int r = 0; r < 4; ++r) {
          int grow = bm + wm + mt * 16 + quad * 4 + r;
          if (grow >= BT_) continue;
          float v = acc[mt][nt][r] + bsf;
          if (gcol < 256) kout[(size_t)grow * 256 + gcol] = v;
          else            vout[(size_t)grow * 256 + gcol - 256] = v;
        }
      }
    }
  }
}

// ---- fused o-proj + residual + LN2 (64 rows/block, grid 512) ------------
__global__ __launch_bounds__(256) void gemm_oln(
    const unsigned short* __restrict__ A, const unsigned short* __restrict__ Bt,
    const float* __restrict__ bias, const unsigned short* __restrict__ xres,
    const float* __restrict__ alpha_ptr,
    const float* __restrict__ g2, const float* __restrict__ b2,
    unsigned short* __restrict__ ybf, float* __restrict__ yf32) {
  __shared__ unsigned short sm[16384];   // 32 KB: staging (10240) / yt (16384)
  unsigned short* lA = sm;               // 64x32 = 2048 shorts
  unsigned short* lB = sm + 2048;        // 256x32 = 8192 shorts
  unsigned short* yt = sm;               // 64x256 = 16384 shorts (aliased)
  const int K = 256;
  int tid = threadIdx.x;
  int bm = blockIdx.x * 64;
  int lane = tid & 63, wave = tid >> 6;
  int wm = (wave & 1) * 32, wn = (wave >> 1) * 128;
  int l15 = lane & 15, quad = lane >> 4;
  int crow = lane >> 2, ccol = (lane & 3) * 8;
  f32x4 acc[2][8] = {};
  for (int k0 = 0; k0 < K; k0 += 32) {
    async_copy16(A + (size_t)(bm + wave * 16 + crow) * K + k0 + ccol,
                 &lA[wave * 512]);
#pragma unroll
    for (int ch = wave; ch < 16; ch += 4)
      async_copy16(Bt + (size_t)(ch * 16 + crow) * K + k0 + ccol,
                   &lB[ch * 512]);
    __syncthreads();
    bf16x8 af[2], bfr[8];
#pragma unroll
    for (int mi = 0; mi < 2; ++mi)
      af[mi] = *reinterpret_cast<const bf16x8*>(&lA[(wm + mi * 16 + l15) * 32 + quad * 8]);
#pragma unroll
    for (int ni = 0; ni < 8; ++ni)
      bfr[ni] = *reinterpret_cast<const bf16x8*>(&lB[(wn + ni * 16 + l15) * 32 + quad * 8]);
#pragma unroll
    for (int mi = 0; mi < 2; ++mi)
#pragma unroll
      for (int ni = 0; ni < 8; ++ni)
        acc[mi][ni] = __builtin_amdgcn_mfma_f32_16x16x32_bf16(af[mi], bfr[ni],
                                                              acc[mi][ni], 0, 0, 0);
    __syncthreads();
  }
  float alpha = *alpha_ptr;
#pragma unroll
  for (int mi = 0; mi < 2; ++mi) {
#pragma unroll
    for (int ni = 0; ni < 8; ++ni) {
      int gcol = wn + ni * 16 + l15;
      float bsf = bias[gcol];
#pragma unroll
      for (int r = 0; r < 4; ++r) {
        int lrow = wm + mi * 16 + quad * 4 + r;
        float v = acc[mi][ni][r] + bsf;
        float y0 = bf2f(xres[(size_t)(bm + lrow) * 256 + gcol]) + alpha * v;
        yt[lrow * 256 + gcol] = f2b(y0);
      }
    }
  }
  __syncthreads();
  for (int it = 0; it < 16; ++it) {
    int row = wave * 16 + it;
    ushort4 u = *reinterpret_cast<const ushort4*>(&yt[row * 256 + lane * 4]);
    float v0 = bf2f(u.x), v1 = bf2f(u.y), v2 = bf2f(u.z), v3 = bf2f(u.w);
    float s = v0 + v1 + v2 + v3;
    float q = v0 * v0 + v1 * v1 + v2 * v2 + v3 * v3;
#pragma unroll
    for (int off = 1; off < 64; off <<= 1) {
      s += __shfl_xor(s, off);
      q += __shfl_xor(q, off);
    }
    float mean = s * (1.0f / 256.0f);
    float var  = q * (1.0f / 256.0f) - mean * mean;
    float rstd = rsqrtf(var + 1e-5f);
    float4 gv = *reinterpret_cast<const float4*>(g2 + lane * 4);
    float4 bv = *reinterpret_cast<const float4*>(b2 + lane * 4);
    float o0 = (v0 - mean) * rstd * gv.x + bv.x;
    float o1 = (v1 - mean) * rstd * gv.y + bv.y;
    float o2 = (v2 - mean) * rstd * gv.z + bv.z;
    float o3 = (v3 - mean) * rstd * gv.w + bv.w;
    size_t base = (size_t)(bm + row) * 256 + lane * 4;
    ushort4 ob;
    ob.x = f2b(o0); ob.y = f2b(o1); ob.z = f2b(o2); ob.w = f2b(o3);
    *reinterpret_cast<ushort4*>(ybf + base) = ob;
    *reinterpret_cast<float4*>(yf32 + base) = make_float4(o0, o1, o2, o3);
  }
}

// ---------- attention v3: MFMA QK^T + packed-index top-5 ------------------
#define SSTR 83
#define VSTR 33
#define NEGBIG -3.0e38f
__device__ __forceinline__ void ins5(float sv, float& tv0, float& tv1,
                                     float& tv2, float& tv3, float& tv4) {
  bool g0 = sv > tv0, g1 = sv > tv1, g2 = sv > tv2, g3 = sv > tv3, g4 = sv > tv4;
  tv4 = g4 ? (g3 ? tv3 : sv) : tv4;
  tv3 = g3 ? (g2 ? tv2 : sv) : tv3;
  tv2 = g2 ? (g1 ? tv1 : sv) : tv2;
  tv1 = g1 ? (g0 ? tv0 : sv) : tv1;
  tv0 = g0 ? sv : tv0;
}
__global__ __launch_bounds__(256) void attn_kernel(
    unsigned short* qa, const float* __restrict__ k,
    const float* __restrict__ v, const float* __restrict__ padb,
    const float* __restrict__ ls_ptr) {
  __shared__ unsigned short qb[64 * 40];
  __shared__ unsigned short kb[80 * 40];
  __shared__ float S[64 * SSTR];
  __shared__ float vs[TT * VSTR];
  __shared__ float rn[64];
  __shared__ float scs[80];
  __shared__ int allpad_s;
  int tid = threadIdx.x;
  int h = blockIdx.y, b = blockIdx.z;
  size_t qbase = ((size_t)b * NPIX + blockIdx.x * 64) * CV_ + h * DH_;
  size_t kvbase = (size_t)b * TT * CV_ + h * DH_;
  float ls = *ls_ptr;
  ls = fminf(fmaxf(ls, -2.0f), 2.0f);
  float scale = expf(ls) * 0.17677669529663687f;
  if (tid == 0) allpad_s = 1;
  __syncthreads();
  int qrow = tid >> 2, qq = tid & 3;
  uint4 qv4 = *reinterpret_cast<const uint4*>(qa + qbase + (size_t)qrow * CV_ + qq * 8);
  *reinterpret_cast<uint4*>(&qb[qrow * 40 + qq * 8]) = qv4;
  {
    float ssq = 0.f;
    unsigned w[4] = {qv4.x, qv4.y, qv4.z, qv4.w};
#pragma unroll
    for (int i = 0; i < 4; ++i) {
      float a = bf2f((unsigned short)(w[i] & 0xFFFF));
      float bb = bf2f((unsigned short)(w[i] >> 16));
      ssq += a * a + bb * bb;
    }
    ssq += __shfl_xor(ssq, 1);
    ssq += __shfl_xor(ssq, 2);
    if (qq == 0) rn[qrow] = scale / fmaxf(sqrtf(ssq), 1e-6f);
  }
  if (tid < 154) {
    int kr = tid >> 1, kh = tid & 1;
    const float* kp = k + kvbase + (size_t)kr * CV_ + kh * 16;
    float4 f0 = *reinterpret_cast<const float4*>(kp);
    float4 f1 = *reinterpret_cast<const float4*>(kp + 4);
    float4 f2 = *reinterpret_cast<const float4*>(kp + 8);
    float4 f3 = *reinterpret_cast<const float4*>(kp + 12);
    float ks2 = f0.x*f0.x + f0.y*f0.y + f0.z*f0.z + f0.w*f0.w
              + f1.x*f1.x + f1.y*f1.y + f1.z*f1.z + f1.w*f1.w
              + f2.x*f2.x + f2.y*f2.y + f2.z*f2.z + f2.w*f2.w
              + f3.x*f3.x + f3.y*f3.y + f3.z*f3.z + f3.w*f3.w;
    uint4 p0, p1;
    p0.x = pack2(f0.x, f0.y); p0.y = pack2(f0.z, f0.w);
    p0.z = pack2(f1.x, f1.y); p0.w = pack2(f1.z, f1.w);
    p1.x = pack2(f2.x, f2.y); p1.y = pack2(f2.z, f2.w);
    p1.z = pack2(f3.x, f3.y); p1.w = pack2(f3.z, f3.w);
    *reinterpret_cast<uint4*>(&kb[kr * 40 + kh * 16]) = p0;
    *reinterpret_cast<uint4*>(&kb[kr * 40 + kh * 16 + 8]) = p1;
    ks2 += __shfl_xor(ks2, 1);
    if (kh == 0) {
      float p = padb[b * TT + kr];
      float sc = (p == 0.0f) ? 1.0f / fmaxf(sqrtf(ks2), 1e-6f) : 0.0f;
      scs[kr] = sc;
      if (sc > 0.0f) allpad_s = 0;
    }
  } else if (tid < 157) {
    scs[77 + (tid - 154)] = 0.0f;
  } else if (tid >= 160 && tid < 172) {
    int i = tid - 160;
    *reinterpret_cast<uint4*>(&kb[(77 + (i >> 2)) * 40 + (i & 3) * 8]) =
        make_uint4(0, 0, 0, 0);
  }
  for (int j = tid; j < TT * 8; j += 256) {
    int t = j >> 3, d4 = j & 7;
    float4 f = *reinterpret_cast<const float4*>(
        v + kvbase + (size_t)t * CV_ + d4 * 4);
    float* vp = &vs[t * VSTR + d4 * 4];
    vp[0] = f.x; vp[1] = f.y; vp[2] = f.z; vp[3] = f.w;
  }
  __syncthreads();
  {
    int lane = tid & 63, wave = tid >> 6;
    int wm = wave * 16;
    int l15 = lane & 15, quad = lane >> 4;
    f32x4 acc[5] = {};
    bf16x8 af = *reinterpret_cast<const bf16x8*>(&qb[(wm + l15) * 40 + quad * 8]);
    bf16x8 bfr[5];
#pragma unroll
    for (int ni = 0; ni < 5; ++ni)
      bfr[ni] = *reinterpret_cast<const bf16x8*>(&kb[(ni * 16 + l15) * 40 + quad * 8]);
#pragma unroll
    for (int ni = 0; ni < 5; ++ni)
      acc[ni] = __builtin_amdgcn_mfma_f32_16x16x32_bf16(af, bfr[ni], acc[ni], 0, 0, 0);
#pragma unroll
    for (int ni = 0; ni < 5; ++ni) {
      int col = ni * 16 + l15;
      float sc = scs[col];
#pragma unroll
      for (int r = 0; r < 4; ++r) {
        int row = wm + quad * 4 + r;
        float val = (sc > 0.0f) ? acc[ni][r] * rn[row] * sc : NEGBIG;
        unsigned pb = (__float_as_uint(val) & 0xFFFFFF80u) | (unsigned)col;
        S[row * SSTR + col] = __uint_as_float(pb);
      }
    }
  }
  __syncthreads();
  int allpad = allpad_s;
  int row = qrow;
  const float* Srow = &S[row * SSTR];
  int t0 = qq * 20, t1 = (qq == 3) ? TT : t0 + 20;
  float tv0 = -INFINITY, tv1 = -INFINITY, tv2 = -INFINITY,
        tv3 = -INFINITY, tv4 = -INFINITY;
  for (int t = t0; t < t1; ++t)
    ins5(Srow[t], tv0, tv1, tv2, tv3, tv4);
#pragma unroll
  for (int m = 1; m <= 2; m <<= 1) {
    float n0 = __shfl_xor(tv0, m), n1 = __shfl_xor(tv1, m),
          n2 = __shfl_xor(tv2, m), n3 = __shfl_xor(tv3, m),
          n4 = __shfl_xor(tv4, m);
    ins5(n0, tv0, tv1, tv2, tv3, tv4);
    ins5(n1, tv0, tv1, tv2, tv3, tv4);
    ins5(n2, tv0, tv1, tv2, tv3, tv4);
    ins5(n3, tv0, tv1, tv2, tv3, tv4);
    ins5(n4, tv0, tv1, tv2, tv3, tv4);
  }
  float o[8];
#pragma unroll
  for (int d = 0; d < 8; ++d) o[d] = 0.f;
  if (!allpad) {
    float e0 = 1.0f;
    float e1 = expf(tv1 - tv0);
    float e2 = expf(tv2 - tv0);
    float e3 = expf(tv3 - tv0);
    float e4 = expf(tv4 - tv0);
    float inv = 1.0f / (e0 + e1 + e2 + e3 + e4);
    int i0 = __float_as_uint(tv0) & 0x7F, i1 = __float_as_uint(tv1) & 0x7F,
        i2 = __float_as_uint(tv2) & 0x7F, i3 = __float_as_uint(tv3) & 0x7F,
        i4 = __float_as_uint(tv4) & 0x7F;
    const float* v0p = &vs[i0 * VSTR + qq * 8];
    const float* v1p = &vs[i1 * VSTR + qq * 8];
    const float* v2p = &vs[i2 * VSTR + qq * 8];
    const float* v3p = &vs[i3 * VSTR + qq * 8];
    const float* v4p = &vs[i4 * VSTR + qq * 8];
#pragma unroll
    for (int d = 0; d < 8; ++d)
      o[d] = (e0 * v0p[d] + e1 * v1p[d] + e2 * v2p[d] + e3 * v3p[d] + e4 * v4p[d]) * inv;
  }
  unsigned short* qp = qa + qbase + (size_t)row * CV_ + qq * 8;
  uint4 ou;
  ou.x = ((unsigned)f2b(o[1]) << 16) | f2b(o[0]);
  ou.y = ((unsigned)f2b(o[3]) << 16) | f2b(o[2]);
  ou.z = ((unsigned)f2b(o[5]) << 16) | f2b(o[4]);
  ou.w = ((unsigned)f2b(o[7]) << 16) | f2b(o[6]);
  *reinterpret_cast<uint4*>(qp) = ou;
}

// ---------- fused FFN: out = y + gelu(y@W1+b1)@W2 + b2 -------------------
// R9: 64-row tiles, 512 blocks (2 blocks/CU!), 512 threads (8 waves).
// LDS = xs 32KB + Hs 16KB + Wb 32KB = 81920 B exactly -> 2 blocks/CU for
// cross-block overlap of the barrier/vmcnt drains. Stage/step/sync skeleton
// and Wb swizzle byte-identical to R8's proven loop (W1c/W2c staging is
// row-count-independent). xs/Hs are unpadded, slot-swizzled like Wb:
// phys slot = (col>>3) ^ ((row>>1)&3)  [all access bases are 8-aligned].
// Per-wave tiles: phase1 acc1[4] (64hid x 16rows), phase2 acc[2][4]
// (32rows x 64cols). Accumulation k-order unchanged -> bit-identical.
__global__ __launch_bounds__(512) void ffn_fused(
    const unsigned short* __restrict__ ybf, const unsigned short* __restrict__ W1T,
    const float* __restrict__ b1f, const unsigned short* __restrict__ W2T,
    const float* __restrict__ b2f, float* __restrict__ yio) {
  __shared__ unsigned short xs[64 * 256];   // 32768 B, slot-swizzled
  __shared__ unsigned short Hs[64 * 128];   // 16384 B, slot-swizzled
  __shared__ unsigned short Wb[16384];      // 32 KB = 2 x 16KB halves
  int tid = threadIdx.x, lane = tid & 63, wave = tid >> 6;  // wave 0..7
  int l15 = lane & 15, quad = lane >> 4;
  int crow = lane >> 2;
  // Wb swizzle (R5-proven): slot(2b) ^= (row>>1)&3
  int ccs = (((lane & 3) ^ ((lane >> 3) & 3)) * 8);  // pre-swizzled global col
  int rsw = ((quad ^ ((l15 >> 1) & 3)) * 8);         // swizzled Wb read col
  int sws = (l15 >> 1) & 3;  // xs/Hs row-swizzle term (row bases are 8-mult)
  int bm = blockIdx.x * 64;
  {  // stage y-tile swizzled; 8 threads/row, 32 shorts each
    int row = tid >> 3, kh8 = (tid & 7) * 4;   // slot base (col/8)
    const unsigned short* src = ybf + (size_t)(bm + row) * 256 + kh8 * 8;
    int sw = (row >> 1) & 3;
    unsigned short* dst = &xs[row * 256];
#pragma unroll
    for (int i = 0; i < 4; ++i)
      *reinterpret_cast<uint4*>(dst + ((kh8 + i) ^ sw) * 8) =
          *reinterpret_cast<const uint4*>(src + i * 8);
  }
  int wm2 = (wave & 1) * 32, wn2 = (wave >> 1) * 64;   // phase2 tile
  int wh1 = (wave & 1) * 64, wr1 = (wave >> 1) * 16;   // phase1 tile
  int row1 = wr1 + l15;                                 // phase1 xs row
  // Running stage pointers (R8-proven, row-count independent):
  const unsigned short* w1p = W1T + (size_t)(wave * 16 + crow) * 256 + ccs;
  const unsigned short* w2p = W2T + (size_t)(wave * 32 + crow) * 1024 + ccs;
  auto stage_step = [&](int p2, int half) {
    unsigned short* buf = &Wb[half * 8192];
    if (p2 < 4) {
      async_copy16(w1p,      &buf[wave * 512]);
      async_copy16(w1p + 32, &buf[4096 + wave * 512]);
      w1p += 64;
      if (p2 == 3) w1p += 32512;         // next chunk: +32768 total
    } else {
      async_copy16(w2p,          &buf[wave * 1024]);
      async_copy16(w2p + 16384,  &buf[wave * 1024 + 512]);
      w2p += 32;                          // 4 steps = +128 = chunk stride
    }
  };
  f32x4 acc[2][4] = {};
  stage_step(0, 0); stage_step(1, 1);
  for (int c = 0; c < 8; ++c) {
    f32x4 acc1[4] = {};
#pragma unroll
    for (int p = 0; p < 8; ++p) {
      // ledger: outstanding = {st:2, st+1:2} except final step ({63:2})
      if (p == 7 && c == 7)
        asm volatile("s_waitcnt vmcnt(0) lgkmcnt(0)" ::: "memory");
      else
        asm volatile("s_waitcnt vmcnt(2) lgkmcnt(0)" ::: "memory");
      __builtin_amdgcn_s_barrier();
      __builtin_amdgcn_sched_barrier(0);
      const unsigned short* buf = &Wb[(p & 1) * 8192];
      if (p < 4) {
#pragma unroll
        for (int sl = 0; sl < 2; ++sl) {
          int k = p * 64 + sl * 32;
          bf16x8 af[4];
#pragma unroll
          for (int mi = 0; mi < 4; ++mi)
            af[mi] = *reinterpret_cast<const bf16x8*>(
                &buf[sl * 4096 + (wh1 + mi * 16 + l15) * 32 + rsw]);
          bf16x8 bx = *reinterpret_cast<const bf16x8*>(
              &xs[row1 * 256 + (((k >> 3) + quad) ^ sws) * 8]);
          __builtin_amdgcn_s_setprio(1);
#pragma unroll
          for (int mi = 0; mi < 4; ++mi)
            acc1[mi] = __builtin_amdgcn_mfma_f32_16x16x32_bf16(
                af[mi], bx, acc1[mi], 0, 0, 0);
          __builtin_amdgcn_s_setprio(0);
        }
        if (p == 3) {   // GELU + bias -> Hs (phase1 of chunk c complete)
#pragma unroll
          for (int mi = 0; mi < 4; ++mi) {
            int hb = wh1 + mi * 16 + quad * 4;
            float b0 = b1f[c * 128 + hb],      b1v = b1f[c * 128 + hb + 1];
            float b2v = b1f[c * 128 + hb + 2], b3 = b1f[c * 128 + hb + 3];
            ushort4 hw;
            hw.x = f2b(gelu_t(acc1[mi][0] + b0));
            hw.y = f2b(gelu_t(acc1[mi][1] + b1v));
            hw.z = f2b(gelu_t(acc1[mi][2] + b2v));
            hw.w = f2b(gelu_t(acc1[mi][3] + b3));
            *reinterpret_cast<ushort4*>(
                &Hs[row1 * 128 + (((hb >> 3) ^ sws) * 8) + (hb & 7)]) = hw;
          }
        }
      } else {
        int kk = (p - 4) * 32;
        bf16x8 af[2], bfr[4];
#pragma unroll
        for (int mi = 0; mi < 2; ++mi) {
          int hrow = wm2 + mi * 16 + l15;
          af[mi] = *reinterpret_cast<const bf16x8*>(
              &Hs[hrow * 128 + (((kk >> 3) + quad) ^ sws) * 8]);
        }
#pragma unroll
        for (int ni = 0; ni < 4; ++ni)
          bfr[ni] = *reinterpret_cast<const bf16x8*>(
              &buf[(wn2 + ni * 16 + l15) * 32 + rsw]);
        __builtin_amdgcn_s_setprio(1);
#pragma unroll
        for (int mi = 0; mi < 2; ++mi)
#pragma unroll
          for (int ni = 0; ni < 4; ++ni)
            acc[mi][ni] = __builtin_amdgcn_mfma_f32_16x16x32_bf16(
                af[mi], bfr[ni], acc[mi][ni], 0, 0, 0);
        __builtin_amdgcn_s_setprio(0);
      }
      __builtin_amdgcn_sched_barrier(0);
      __builtin_amdgcn_s_barrier();
      __builtin_amdgcn_sched_barrier(0);
      if (c < 7 || p < 6)
        stage_step((p + 2) & 7, p & 1);
    }
  }
  // ---- epilogue: out = resid + acc + b2 (fp32 RMW, thread-owned) ----
#pragma unroll
  for (int mi = 0; mi < 2; ++mi)
#pragma unroll
    for (int ni = 0; ni < 4; ++ni) {
      int col = wn2 + ni * 16 + l15;
      float bs = b2f[col];
#pragma unroll
      for (int r = 0; r < 4; ++r) {
        int g = bm + wm2 + mi * 16 + quad * 4 + r;
        size_t oi = (size_t)g * 256 + col;
        yio[oi] = yio[oi] + acc[mi][ni][r] + bs;
      }
    }
}

extern "C" void kernel_launch(void* const* d_in, const int* in_sizes, int n_in,
                              void* d_out, int out_size, void* d_ws, size_t ws_size,
                              hipStream_t stream) {
  const float* visual = (const float*)d_in[0];
  const float* text   = (const float*)d_in[1];
  const float* Wq  = (const float*)d_in[2];
  const float* bq  = (const float*)d_in[3];
  const float* Wk  = (const float*)d_in[4];
  const float* bk  = (const float*)d_in[5];
  const float* Wv  = (const float*)d_in[6];
  const float* bv  = (const float*)d_in[7];
  const float* Wo  = (const float*)d_in[8];
  const float* bo  = (const float*)d_in[9];
  const float* g1  = (const float*)d_in[10];
  const float* b1  = (const float*)d_in[11];
  const float* g2  = (const float*)d_in[12];
  const float* b2  = (const float*)d_in[13];
  const float* W1  = (const float*)d_in[14];
  const float* bf1 = (const float*)d_in[15];
  const float* W2  = (const float*)d_in[16];
  const float* bff2 = (const float*)d_in[17];
  const float* lsc = (const float*)d_in[18];
  const float* alp = (const float*)d_in[19];

  char* ws = (char*)d_ws;
  size_t off = 0;
  auto alloc = [&](size_t bytes) -> char* {
    char* p = ws + off;
    off += (bytes + 255) & ~(size_t)255;
    return p;
  };
  unsigned short* WqT = (unsigned short*)alloc((size_t)65536 * 2);
  unsigned short* WkT = (unsigned short*)alloc((size_t)131072 * 2);  // contiguous
  unsigned short* WvT = (unsigned short*)alloc((size_t)131072 * 2);  // with WkT
  unsigned short* WoT = (unsigned short*)alloc((size_t)65536 * 2);
  unsigned short* W1T = (unsigned short*)alloc((size_t)262144 * 2);
  unsigned short* W2T = (unsigned short*)alloc((size_t)262144 * 2);
  float*          bkv  = (float*)alloc(512 * 4);
  float*          kbuf = (float*)alloc((size_t)BT_ * CV_ * 4);
  float*          vbuf = (float*)alloc((size_t)BT_ * CV_ * 4);
  float*          padb = (float*)alloc((size_t)BT_ * 4);
  char* U = ws + off;                      // total ws ~= 36.3 MB
  unsigned short* xbuf = (unsigned short*)U;
  unsigned short* qbuf = (unsigned short*)(U + 16777216);
  float*          ybuf = (float*)d_out;

  // 1. prep: LN1 + LDS-tiled weight convT + kv bias + pad mask
  prep_kernel<<<8571, 256, 0, stream>>>(visual, g1, b1, xbuf,
                                        Wq, Wk, Wv, Wo, W1, W2,
                                        WqT, WkT, WvT, WoT, W1T, W2T,
                                        bk, bv, bkv, text, padb);
  // 2. q-proj + kv GEMM merged
  qkv_kernel<<<592, 256, 0, stream>>>(xbuf, WqT, bq, qbuf,
                                      text, WkT, bkv, kbuf, vbuf);
  // 3. attention v3: qbuf -> qbuf in place
  attn_kernel<<<dim3(64, NH_, NB), 256, 0, stream>>>(qbuf, kbuf, vbuf, padb, lsc);
  // 4. fused o-proj + residual + LN2: y bf16 (xbuf) + y fp32 (d_out)
  gemm_oln<<<512, 256, 0, stream>>>(qbuf, WoT, bo, xbuf, alp, g2, b2,
                                    xbuf, ybuf);
  // 5. fused FFN: 64-row tiles, 2 blocks/CU (reads y bf16 + fp32 resid RMW)
  ffn_fused<<<512, 512, 0, stream>>>(xbuf, W1T, bf1, W2T, bff2, ybuf);
}

// Round 10
// 275.598 us; speedup vs baseline: 1.0358x; 1.0176x over previous
//
#include <hip/hip_runtime.h>
#include <math.h>

// Problem constants
#define NB   8
#define NPIX 4096          // H*W
#define MROW 32768         // B*H*W
#define CV_  256
#define TT   77
#define CT_  512
#define NH_  8
#define DH_  32
#define BT_  616           // B*T

typedef __bf16 bf16x8 __attribute__((ext_vector_type(8)));
typedef float  f32x4  __attribute__((ext_vector_type(4)));

__device__ __forceinline__ float bf2f(unsigned short u) {
  return __uint_as_float(((unsigned)u) << 16);
}
__device__ __forceinline__ unsigned short f2b(float f) {
  unsigned u = __float_as_uint(f);
  return (unsigned short)((u + 0x7FFFu + ((u >> 16) & 1u)) >> 16);
}
__device__ __forceinline__ unsigned pack2(float lo, float hi) {
  return ((unsigned)f2b(hi) << 16) | (unsigned)f2b(lo);
}
__device__ __forceinline__ void async_copy16(const unsigned short* g,
                                             unsigned short* l) {
  __builtin_amdgcn_global_load_lds(
      (const __attribute__((address_space(1))) void*)g,
      (__attribute__((address_space(3))) void*)l, 16, 0, 0);
}
// tanh-GELU: 0.5*v*(1+tanh(0.79788456*(v+0.044715 v^3))) = v - v/(e^{2u}+1)
__device__ __forceinline__ float gelu_t(float v) {
  float p = v * fmaf(0.0713548162726f, v * v, 1.59576912161f);
  float e = __expf(p);
  return v - v / (e + 1.0f);
}

// -- prep: LN1 (0..8191) + LDS-tiled weight convT (8192..8415) +
//          kv bias (8416) + pad mask (8417..8570) --------------------------
__global__ __launch_bounds__(256) void prep_kernel(
    const float* __restrict__ visual, const float* __restrict__ g1,
    const float* __restrict__ b1, unsigned short* __restrict__ xbuf,
    const float* __restrict__ s0, const float* __restrict__ s1,
    const float* __restrict__ s2, const float* __restrict__ s3,
    const float* __restrict__ s4, const float* __restrict__ s5,
    unsigned short* __restrict__ d0, unsigned short* __restrict__ d1,
    unsigned short* __restrict__ d2, unsigned short* __restrict__ d3,
    unsigned short* __restrict__ d4, unsigned short* __restrict__ d5,
    const float* __restrict__ bk, const float* __restrict__ bv,
    float* __restrict__ bkv, const float* __restrict__ text,
    float* __restrict__ padb) {
  __shared__ unsigned short tl[64 * 68];   // 8704 B transpose tile
  int bx = blockIdx.x;
  int tid = threadIdx.x;
  int wave = tid >> 6, lane = tid & 63;
  if (bx < 8192) {                       // LN1: visual fp32 -> x bf16
    int row = bx * 4 + wave;
    size_t base = (size_t)row * 256 + lane * 4;
    float4 f = *reinterpret_cast<const float4*>(visual + base);
    float v0 = f.x, v1 = f.y, v2 = f.z, v3 = f.w;
    float s = v0 + v1 + v2 + v3;
    float q = v0 * v0 + v1 * v1 + v2 * v2 + v3 * v3;
#pragma unroll
    for (int off = 1; off < 64; off <<= 1) {
      s += __shfl_xor(s, off);
      q += __shfl_xor(q, off);
    }
    float mean = s * (1.0f / 256.0f);
    float var  = q * (1.0f / 256.0f) - mean * mean;
    float rstd = rsqrtf(var + 1e-5f);
    float4 gv = *reinterpret_cast<const float4*>(g1 + lane * 4);
    float4 bv4 = *reinterpret_cast<const float4*>(b1 + lane * 4);
    ushort4 o;
    o.x = f2b((v0 - mean) * rstd * gv.x + bv4.x);
    o.y = f2b((v1 - mean) * rstd * gv.y + bv4.y);
    o.z = f2b((v2 - mean) * rstd * gv.z + bv4.z);
    o.w = f2b((v3 - mean) * rstd * gv.w + bv4.w);
    *reinterpret_cast<ushort4*>(xbuf + base) = o;
    return;
  }
  if (bx < 8416) {                       // LDS-tiled 64x64 transpose
    int ti = bx - 8192;                  // 0..223
    const float* src; unsigned short* dst; int R, C, m;
    if      (ti < 16)  { src = s0; dst = d0; R = 256;  C = 256;  m = ti; }
    else if (ti < 48)  { src = s1; dst = d1; R = 512;  C = 256;  m = ti - 16; }
    else if (ti < 80)  { src = s2; dst = d2; R = 512;  C = 256;  m = ti - 48; }
    else if (ti < 96)  { src = s3; dst = d3; R = 256;  C = 256;  m = ti - 80; }
    else if (ti < 160) { src = s4; dst = d4; R = 256;  C = 1024; m = ti - 96; }
    else               { src = s5; dst = d5; R = 1024; C = 256;  m = ti - 160; }
    int tpc = C >> 6;
    int tr = m / tpc, tc = m % tpc;
#pragma unroll
    for (int i = 0; i < 4; ++i) {
      int lin = tid + i * 256;           // 0..1023
      int r = lin >> 4, c4 = (lin & 15) * 4;
      float4 f = *reinterpret_cast<const float4*>(
          src + (size_t)(tr * 64 + r) * C + tc * 64 + c4);
      tl[(c4 + 0) * 68 + r] = f2b(f.x);
      tl[(c4 + 1) * 68 + r] = f2b(f.y);
      tl[(c4 + 2) * 68 + r] = f2b(f.z);
      tl[(c4 + 3) * 68 + r] = f2b(f.w);
    }
    __syncthreads();
#pragma unroll
    for (int i = 0; i < 4; ++i) {
      int lin = tid + i * 256;
      int c = lin >> 4, r4 = (lin & 15) * 4;
      ushort4 u = *reinterpret_cast<const ushort4*>(&tl[c * 68 + r4]);
      *reinterpret_cast<ushort4*>(
          dst + (size_t)(tc * 64 + c) * R + tr * 64 + r4) = u;
    }
    return;
  }
  if (bx == 8416) {                      // kv bias concat
    bkv[tid] = bk[tid];
    bkv[256 + tid] = bv[tid];
    return;
  }
  {                                      // pad mask: one wave per (b,t) row
    int row = (bx - 8417) * 4 + wave;    // 0..615
    const float* tr = text + (size_t)row * CT_ + lane * 8;
    float4 f0 = *reinterpret_cast<const float4*>(tr);
    float4 f1 = *reinterpret_cast<const float4*>(tr + 4);
    float s = fabsf(f0.x) + fabsf(f0.y) + fabsf(f0.z) + fabsf(f0.w)
            + fabsf(f1.x) + fabsf(f1.y) + fabsf(f1.z) + fabsf(f1.w);
#pragma unroll
    for (int off = 1; off < 64; off <<= 1) s += __shfl_xor(s, off);
    if (lane == 0) padb[row] = (s <= 1e-6f) ? 1.0f : 0.0f;
  }
}

// ---- merged q-proj (blocks 0..511) + kv GEMM (blocks 512..591) ----------
__global__ __launch_bounds__(256) void qkv_kernel(
    const unsigned short* __restrict__ xb, const unsigned short* __restrict__ WqT,
    const float* __restrict__ bq, unsigned short* __restrict__ qout,
    const float* __restrict__ text, const unsigned short* __restrict__ WkvT,
    const float* __restrict__ bkv, float* __restrict__ kout,
    float* __restrict__ vout) {
  __shared__ unsigned short lA[4096];
  __shared__ unsigned short lB[4096];
  int tid = threadIdx.x;
  int lane = tid & 63, wave = tid >> 6;
  int l15 = lane & 15, quad = lane >> 4;
  if (blockIdx.x < 512) {
    // ---- q-proj: 128x128 tile, K=256, m97 async staging ----
    int bm = (blockIdx.x >> 1) * 128, bn = (blockIdx.x & 1) * 128;
    int wm = (wave & 1) * 64, wn = (wave >> 1) * 64;
    int crow = lane >> 2, ccol = (lane & 3) * 8;
    f32x4 acc[4][4] = {};
    for (int k0 = 0; k0 < 256; k0 += 32) {
#pragma unroll
      for (int ch = 0; ch < 2; ++ch) {
        int c = wave * 2 + ch;
        async_copy16(xb + (size_t)(bm + c * 16 + crow) * 256 + k0 + ccol,
                     &lA[c * 512]);
        async_copy16(WqT + (size_t)(bn + c * 16 + crow) * 256 + k0 + ccol,
                     &lB[c * 512]);
      }
      __syncthreads();
      bf16x8 af[4], bfr[4];
#pragma unroll
      for (int mi = 0; mi < 4; ++mi)
        af[mi] = *reinterpret_cast<const bf16x8*>(&lA[(wm + mi * 16 + l15) * 32 + quad * 8]);
#pragma unroll
      for (int ni = 0; ni < 4; ++ni)
        bfr[ni] = *reinterpret_cast<const bf16x8*>(&lB[(wn + ni * 16 + l15) * 32 + quad * 8]);
#pragma unroll
      for (int mi = 0; mi < 4; ++mi)
#pragma unroll
        for (int ni = 0; ni < 4; ++ni)
          acc[mi][ni] = __builtin_amdgcn_mfma_f32_16x16x32_bf16(af[mi], bfr[ni],
                                                                acc[mi][ni], 0, 0, 0);
      __syncthreads();
    }
#pragma unroll
    for (int mi = 0; mi < 4; ++mi) {
#pragma unroll
      for (int ni = 0; ni < 4; ++ni) {
        int gcol = bn + wn + ni * 16 + l15;
        float bsf = bq[gcol];
#pragma unroll
        for (int r = 0; r < 4; ++r) {
          int grow = bm + wm + mi * 16 + quad * 4 + r;
          qout[(size_t)grow * 256 + gcol] = f2b(acc[mi][ni][r] + bsf);
        }
      }
    }
  } else {
    // ---- kv: 64x64 tile over (616, 512), K=512, fp32 A pack ----
    int i = blockIdx.x - 512;
    int bm = (i % 10) * 64, bn = (i / 10) * 64;
    int srow = tid >> 2, sc8 = (tid & 3) * 8;
    int wm = (wave & 1) * 32, wn = (wave >> 1) * 32;
    f32x4 acc[2][2] = {};
    int gm = bm + srow, gn = bn + srow;
    const bool aok = (gm < BT_);
    for (int k0 = 0; k0 < CT_; k0 += 32) {
      uint4 apk = make_uint4(0, 0, 0, 0);
      if (aok) {
        const float* Af = text + (size_t)gm * CT_ + k0 + sc8;
        float4 f0 = *reinterpret_cast<const float4*>(Af);
        float4 f1 = *reinterpret_cast<const float4*>(Af + 4);
        apk.x = pack2(f0.x, f0.y); apk.y = pack2(f0.z, f0.w);
        apk.z = pack2(f1.x, f1.y); apk.w = pack2(f1.z, f1.w);
      }
      uint4 bpk = *reinterpret_cast<const uint4*>(WkvT + (size_t)gn * CT_ + k0 + sc8);
      *reinterpret_cast<uint4*>(&lA[srow * 40 + sc8]) = apk;
      *reinterpret_cast<uint4*>(&lB[srow * 40 + sc8]) = bpk;
      __syncthreads();
      bf16x8 a0 = *reinterpret_cast<const bf16x8*>(&lA[(wm + l15) * 40 + quad * 8]);
      bf16x8 a1 = *reinterpret_cast<const bf16x8*>(&lA[(wm + 16 + l15) * 40 + quad * 8]);
      bf16x8 b0 = *reinterpret_cast<const bf16x8*>(&lB[(wn + l15) * 40 + quad * 8]);
      bf16x8 b1 = *reinterpret_cast<const bf16x8*>(&lB[(wn + 16 + l15) * 40 + quad * 8]);
      acc[0][0] = __builtin_amdgcn_mfma_f32_16x16x32_bf16(a0, b0, acc[0][0], 0, 0, 0);
      acc[0][1] = __builtin_amdgcn_mfma_f32_16x16x32_bf16(a0, b1, acc[0][1], 0, 0, 0);
      acc[1][0] = __builtin_amdgcn_mfma_f32_16x16x32_bf16(a1, b0, acc[1][0], 0, 0, 0);
      acc[1][1] = __builtin_amdgcn_mfma_f32_16x16x32_bf16(a1, b1, acc[1][1], 0, 0, 0);
      __syncthreads();
    }
#pragma unroll
    for (int mt = 0; mt < 2; ++mt) {
#pragma unroll
      for (int nt = 0; nt < 2; ++nt) {
        int gcol = bn + wn + nt * 16 + l15;
        float bsf = bkv[gcol];
#pragma unroll
        for (int r = 0; r < 4; ++r) {
          int grow = bm + wm + mt * 16 + quad * 4 + r;
          if (grow >= BT_) continue;
          float v = acc[mt][nt][r] + bsf;
          if (gcol < 256) kout[(size_t)grow * 256 + gcol] = v;
          else            vout[(size_t)grow * 256 + gcol - 256] = v;
        }
      }
    }
  }
}

// ---- fused o-proj + residual + LN2 (64 rows/block, grid 512) ------------
__global__ __launch_bounds__(256) void gemm_oln(
    const unsigned short* __restrict__ A, const unsigned short* __restrict__ Bt,
    const float* __restrict__ bias, const unsigned short* __restrict__ xres,
    const float* __restrict__ alpha_ptr,
    const float* __restrict__ g2, const float* __restrict__ b2,
    unsigned short* __restrict__ ybf, float* __restrict__ yf32) {
  __shared__ unsigned short sm[16384];   // 32 KB: staging (10240) / yt (16384)
  unsigned short* lA = sm;               // 64x32 = 2048 shorts
  unsigned short* lB = sm + 2048;        // 256x32 = 8192 shorts
  unsigned short* yt = sm;               // 64x256 = 16384 shorts (aliased)
  const int K = 256;
  int tid = threadIdx.x;
  int bm = blockIdx.x * 64;
  int lane = tid & 63, wave = tid >> 6;
  int wm = (wave & 1) * 32, wn = (wave >> 1) * 128;
  int l15 = lane & 15, quad = lane >> 4;
  int crow = lane >> 2, ccol = (lane & 3) * 8;
  f32x4 acc[2][8] = {};
  for (int k0 = 0; k0 < K; k0 += 32) {
    async_copy16(A + (size_t)(bm + wave * 16 + crow) * K + k0 + ccol,
                 &lA[wave * 512]);
#pragma unroll
    for (int ch = wave; ch < 16; ch += 4)
      async_copy16(Bt + (size_t)(ch * 16 + crow) * K + k0 + ccol,
                   &lB[ch * 512]);
    __syncthreads();
    bf16x8 af[2], bfr[8];
#pragma unroll
    for (int mi = 0; mi < 2; ++mi)
      af[mi] = *reinterpret_cast<const bf16x8*>(&lA[(wm + mi * 16 + l15) * 32 + quad * 8]);
#pragma unroll
    for (int ni = 0; ni < 8; ++ni)
      bfr[ni] = *reinterpret_cast<const bf16x8*>(&lB[(wn + ni * 16 + l15) * 32 + quad * 8]);
#pragma unroll
    for (int mi = 0; mi < 2; ++mi)
#pragma unroll
      for (int ni = 0; ni < 8; ++ni)
        acc[mi][ni] = __builtin_amdgcn_mfma_f32_16x16x32_bf16(af[mi], bfr[ni],
                                                              acc[mi][ni], 0, 0, 0);
    __syncthreads();
  }
  float alpha = *alpha_ptr;
#pragma unroll
  for (int mi = 0; mi < 2; ++mi) {
#pragma unroll
    for (int ni = 0; ni < 8; ++ni) {
      int gcol = wn + ni * 16 + l15;
      float bsf = bias[gcol];
#pragma unroll
      for (int r = 0; r < 4; ++r) {
        int lrow = wm + mi * 16 + quad * 4 + r;
        float v = acc[mi][ni][r] + bsf;
        float y0 = bf2f(xres[(size_t)(bm + lrow) * 256 + gcol]) + alpha * v;
        yt[lrow * 256 + gcol] = f2b(y0);
      }
    }
  }
  __syncthreads();
  for (int it = 0; it < 16; ++it) {
    int row = wave * 16 + it;
    ushort4 u = *reinterpret_cast<const ushort4*>(&yt[row * 256 + lane * 4]);
    float v0 = bf2f(u.x), v1 = bf2f(u.y), v2 = bf2f(u.z), v3 = bf2f(u.w);
    float s = v0 + v1 + v2 + v3;
    float q = v0 * v0 + v1 * v1 + v2 * v2 + v3 * v3;
#pragma unroll
    for (int off = 1; off < 64; off <<= 1) {
      s += __shfl_xor(s, off);
      q += __shfl_xor(q, off);
    }
    float mean = s * (1.0f / 256.0f);
    float var  = q * (1.0f / 256.0f) - mean * mean;
    float rstd = rsqrtf(var + 1e-5f);
    float4 gv = *reinterpret_cast<const float4*>(g2 + lane * 4);
    float4 bv = *reinterpret_cast<const float4*>(b2 + lane * 4);
    float o0 = (v0 - mean) * rstd * gv.x + bv.x;
    float o1 = (v1 - mean) * rstd * gv.y + bv.y;
    float o2 = (v2 - mean) * rstd * gv.z + bv.z;
    float o3 = (v3 - mean) * rstd * gv.w + bv.w;
    size_t base = (size_t)(bm + row) * 256 + lane * 4;
    ushort4 ob;
    ob.x = f2b(o0); ob.y = f2b(o1); ob.z = f2b(o2); ob.w = f2b(o3);
    *reinterpret_cast<ushort4*>(ybf + base) = ob;
    *reinterpret_cast<float4*>(yf32 + base) = make_float4(o0, o1, o2, o3);
  }
}

// ---------- attention v3: MFMA QK^T + packed-index top-5 ------------------
#define SSTR 83
#define VSTR 33
#define NEGBIG -3.0e38f
__device__ __forceinline__ void ins5(float sv, float& tv0, float& tv1,
                                     float& tv2, float& tv3, float& tv4) {
  bool g0 = sv > tv0, g1 = sv > tv1, g2 = sv > tv2, g3 = sv > tv3, g4 = sv > tv4;
  tv4 = g4 ? (g3 ? tv3 : sv) : tv4;
  tv3 = g3 ? (g2 ? tv2 : sv) : tv3;
  tv2 = g2 ? (g1 ? tv1 : sv) : tv2;
  tv1 = g1 ? (g0 ? tv0 : sv) : tv1;
  tv0 = g0 ? sv : tv0;
}
__global__ __launch_bounds__(256) void attn_kernel(
    unsigned short* qa, const float* __restrict__ k,
    const float* __restrict__ v, const float* __restrict__ padb,
    const float* __restrict__ ls_ptr) {
  __shared__ unsigned short qb[64 * 40];
  __shared__ unsigned short kb[80 * 40];
  __shared__ float S[64 * SSTR];
  __shared__ float vs[TT * VSTR];
  __shared__ float rn[64];
  __shared__ float scs[80];
  __shared__ int allpad_s;
  int tid = threadIdx.x;
  int h = blockIdx.y, b = blockIdx.z;
  size_t qbase = ((size_t)b * NPIX + blockIdx.x * 64) * CV_ + h * DH_;
  size_t kvbase = (size_t)b * TT * CV_ + h * DH_;
  float ls = *ls_ptr;
  ls = fminf(fmaxf(ls, -2.0f), 2.0f);
  float scale = expf(ls) * 0.17677669529663687f;
  if (tid == 0) allpad_s = 1;
  __syncthreads();
  int qrow = tid >> 2, qq = tid & 3;
  uint4 qv4 = *reinterpret_cast<const uint4*>(qa + qbase + (size_t)qrow * CV_ + qq * 8);
  *reinterpret_cast<uint4*>(&qb[qrow * 40 + qq * 8]) = qv4;
  {
    float ssq = 0.f;
    unsigned w[4] = {qv4.x, qv4.y, qv4.z, qv4.w};
#pragma unroll
    for (int i = 0; i < 4; ++i) {
      float a = bf2f((unsigned short)(w[i] & 0xFFFF));
      float bb = bf2f((unsigned short)(w[i] >> 16));
      ssq += a * a + bb * bb;
    }
    ssq += __shfl_xor(ssq, 1);
    ssq += __shfl_xor(ssq, 2);
    if (qq == 0) rn[qrow] = scale / fmaxf(sqrtf(ssq), 1e-6f);
  }
  if (tid < 154) {
    int kr = tid >> 1, kh = tid & 1;
    const float* kp = k + kvbase + (size_t)kr * CV_ + kh * 16;
    float4 f0 = *reinterpret_cast<const float4*>(kp);
    float4 f1 = *reinterpret_cast<const float4*>(kp + 4);
    float4 f2 = *reinterpret_cast<const float4*>(kp + 8);
    float4 f3 = *reinterpret_cast<const float4*>(kp + 12);
    float ks2 = f0.x*f0.x + f0.y*f0.y + f0.z*f0.z + f0.w*f0.w
              + f1.x*f1.x + f1.y*f1.y + f1.z*f1.z + f1.w*f1.w
              + f2.x*f2.x + f2.y*f2.y + f2.z*f2.z + f2.w*f2.w
              + f3.x*f3.x + f3.y*f3.y + f3.z*f3.z + f3.w*f3.w;
    uint4 p0, p1;
    p0.x = pack2(f0.x, f0.y); p0.y = pack2(f0.z, f0.w);
    p0.z = pack2(f1.x, f1.y); p0.w = pack2(f1.z, f1.w);
    p1.x = pack2(f2.x, f2.y); p1.y = pack2(f2.z, f2.w);
    p1.z = pack2(f3.x, f3.y); p1.w = pack2(f3.z, f3.w);
    *reinterpret_cast<uint4*>(&kb[kr * 40 + kh * 16]) = p0;
    *reinterpret_cast<uint4*>(&kb[kr * 40 + kh * 16 + 8]) = p1;
    ks2 += __shfl_xor(ks2, 1);
    if (kh == 0) {
      float p = padb[b * TT + kr];
      float sc = (p == 0.0f) ? 1.0f / fmaxf(sqrtf(ks2), 1e-6f) : 0.0f;
      scs[kr] = sc;
      if (sc > 0.0f) allpad_s = 0;
    }
  } else if (tid < 157) {
    scs[77 + (tid - 154)] = 0.0f;
  } else if (tid >= 160 && tid < 172) {
    int i = tid - 160;
    *reinterpret_cast<uint4*>(&kb[(77 + (i >> 2)) * 40 + (i & 3) * 8]) =
        make_uint4(0, 0, 0, 0);
  }
  for (int j = tid; j < TT * 8; j += 256) {
    int t = j >> 3, d4 = j & 7;
    float4 f = *reinterpret_cast<const float4*>(
        v + kvbase + (size_t)t * CV_ + d4 * 4);
    float* vp = &vs[t * VSTR + d4 * 4];
    vp[0] = f.x; vp[1] = f.y; vp[2] = f.z; vp[3] = f.w;
  }
  __syncthreads();
  {
    int lane = tid & 63, wave = tid >> 6;
    int wm = wave * 16;
    int l15 = lane & 15, quad = lane >> 4;
    f32x4 acc[5] = {};
    bf16x8 af = *reinterpret_cast<const bf16x8*>(&qb[(wm + l15) * 40 + quad * 8]);
    bf16x8 bfr[5];
#pragma unroll
    for (int ni = 0; ni < 5; ++ni)
      bfr[ni] = *reinterpret_cast<const bf16x8*>(&kb[(ni * 16 + l15) * 40 + quad * 8]);
#pragma unroll
    for (int ni = 0; ni < 5; ++ni)
      acc[ni] = __builtin_amdgcn_mfma_f32_16x16x32_bf16(af, bfr[ni], acc[ni], 0, 0, 0);
#pragma unroll
    for (int ni = 0; ni < 5; ++ni) {
      int col = ni * 16 + l15;
      float sc = scs[col];
#pragma unroll
      for (int r = 0; r < 4; ++r) {
        int row = wm + quad * 4 + r;
        float val = (sc > 0.0f) ? acc[ni][r] * rn[row] * sc : NEGBIG;
        unsigned pb = (__float_as_uint(val) & 0xFFFFFF80u) | (unsigned)col;
        S[row * SSTR + col] = __uint_as_float(pb);
      }
    }
  }
  __syncthreads();
  int allpad = allpad_s;
  int row = qrow;
  const float* Srow = &S[row * SSTR];
  int t0 = qq * 20, t1 = (qq == 3) ? TT : t0 + 20;
  float tv0 = -INFINITY, tv1 = -INFINITY, tv2 = -INFINITY,
        tv3 = -INFINITY, tv4 = -INFINITY;
  for (int t = t0; t < t1; ++t)
    ins5(Srow[t], tv0, tv1, tv2, tv3, tv4);
#pragma unroll
  for (int m = 1; m <= 2; m <<= 1) {
    float n0 = __shfl_xor(tv0, m), n1 = __shfl_xor(tv1, m),
          n2 = __shfl_xor(tv2, m), n3 = __shfl_xor(tv3, m),
          n4 = __shfl_xor(tv4, m);
    ins5(n0, tv0, tv1, tv2, tv3, tv4);
    ins5(n1, tv0, tv1, tv2, tv3, tv4);
    ins5(n2, tv0, tv1, tv2, tv3, tv4);
    ins5(n3, tv0, tv1, tv2, tv3, tv4);
    ins5(n4, tv0, tv1, tv2, tv3, tv4);
  }
  float o[8];
#pragma unroll
  for (int d = 0; d < 8; ++d) o[d] = 0.f;
  if (!allpad) {
    float e0 = 1.0f;
    float e1 = expf(tv1 - tv0);
    float e2 = expf(tv2 - tv0);
    float e3 = expf(tv3 - tv0);
    float e4 = expf(tv4 - tv0);
    float inv = 1.0f / (e0 + e1 + e2 + e3 + e4);
    int i0 = __float_as_uint(tv0) & 0x7F, i1 = __float_as_uint(tv1) & 0x7F,
        i2 = __float_as_uint(tv2) & 0x7F, i3 = __float_as_uint(tv3) & 0x7F,
        i4 = __float_as_uint(tv4) & 0x7F;
    const float* v0p = &vs[i0 * VSTR + qq * 8];
    const float* v1p = &vs[i1 * VSTR + qq * 8];
    const float* v2p = &vs[i2 * VSTR + qq * 8];
    const float* v3p = &vs[i3 * VSTR + qq * 8];
    const float* v4p = &vs[i4 * VSTR + qq * 8];
#pragma unroll
    for (int d = 0; d < 8; ++d)
      o[d] = (e0 * v0p[d] + e1 * v1p[d] + e2 * v2p[d] + e3 * v3p[d] + e4 * v4p[d]) * inv;
  }
  unsigned short* qp = qa + qbase + (size_t)row * CV_ + qq * 8;
  uint4 ou;
  ou.x = ((unsigned)f2b(o[1]) << 16) | f2b(o[0]);
  ou.y = ((unsigned)f2b(o[3]) << 16) | f2b(o[2]);
  ou.z = ((unsigned)f2b(o[5]) << 16) | f2b(o[4]);
  ou.w = ((unsigned)f2b(o[7]) << 16) | f2b(o[6]);
  *reinterpret_cast<uint4*>(qp) = ou;
}

// ---------- fused FFN: out = y + gelu(y@W1+b1)@W2 + b2 -------------------
// R10: R9 structure (64-row tiles, 512 blocks = 2 blocks/CU, 8 waves,
// LDS 81920 B) with the xs/Hs swizzle widened from 2-bit to 3-bit:
// phys slot = slot ^ (row & 7). With unpadded 512B/256B row strides, a
// b128 read is conflict-free iff slot&7 spans all 8 bank-groups evenly;
// the old 2-bit XOR (quad^2bit) spanned only 4 -> 2-way conflict (R9:
// 8.26M conflicts). All row bases are multiples of 8 -> row&7 == l15&7
// on every access path; XOR of low 3 bits keeps slots in range.
// Wb swizzle (32-short rows, R5-proven 2-bit) unchanged. Numerics
// bit-identical (storage location only).
__global__ __launch_bounds__(512) void ffn_fused(
    const unsigned short* __restrict__ ybf, const unsigned short* __restrict__ W1T,
    const float* __restrict__ b1f, const unsigned short* __restrict__ W2T,
    const float* __restrict__ b2f, float* __restrict__ yio) {
  __shared__ unsigned short xs[64 * 256];   // 32768 B, slot-swizzled (3-bit)
  __shared__ unsigned short Hs[64 * 128];   // 16384 B, slot-swizzled (3-bit)
  __shared__ unsigned short Wb[16384];      // 32 KB = 2 x 16KB halves
  int tid = threadIdx.x, lane = tid & 63, wave = tid >> 6;  // wave 0..7
  int l15 = lane & 15, quad = lane >> 4;
  int crow = lane >> 2;
  // Wb swizzle (R5-proven): slot(2b) ^= (row>>1)&3
  int ccs = (((lane & 3) ^ ((lane >> 3) & 3)) * 8);  // pre-swizzled global col
  int rsw = ((quad ^ ((l15 >> 1) & 3)) * 8);         // swizzled Wb read col
  int sws = l15 & 7;         // xs/Hs 3-bit row-swizzle (row bases 8-aligned)
  int bm = blockIdx.x * 64;
  {  // stage y-tile swizzled; 8 threads/row, 32 shorts each
    int row = tid >> 3, kh8 = (tid & 7) * 4;   // slot base (col/8)
    const unsigned short* src = ybf + (size_t)(bm + row) * 256 + kh8 * 8;
    int sw = row & 7;
    unsigned short* dst = &xs[row * 256];
#pragma unroll
    for (int i = 0; i < 4; ++i)
      *reinterpret_cast<uint4*>(dst + ((kh8 + i) ^ sw) * 8) =
          *reinterpret_cast<const uint4*>(src + i * 8);
  }
  int wm2 = (wave & 1) * 32, wn2 = (wave >> 1) * 64;   // phase2 tile
  int wh1 = (wave & 1) * 64, wr1 = (wave >> 1) * 16;   // phase1 tile
  int row1 = wr1 + l15;                                 // phase1 xs row
  // Running stage pointers (R8-proven, row-count independent):
  const unsigned short* w1p = W1T + (size_t)(wave * 16 + crow) * 256 + ccs;
  const unsigned short* w2p = W2T + (size_t)(wave * 32 + crow) * 1024 + ccs;
  auto stage_step = [&](int p2, int half) {
    unsigned short* buf = &Wb[half * 8192];
    if (p2 < 4) {
      async_copy16(w1p,      &buf[wave * 512]);
      async_copy16(w1p + 32, &buf[4096 + wave * 512]);
      w1p += 64;
      if (p2 == 3) w1p += 32512;         // next chunk: +32768 total
    } else {
      async_copy16(w2p,          &buf[wave * 1024]);
      async_copy16(w2p + 16384,  &buf[wave * 1024 + 512]);
      w2p += 32;                          // 4 steps = +128 = chunk stride
    }
  };
  f32x4 acc[2][4] = {};
  stage_step(0, 0); stage_step(1, 1);
  for (int c = 0; c < 8; ++c) {
    f32x4 acc1[4] = {};
#pragma unroll
    for (int p = 0; p < 8; ++p) {
      // ledger: outstanding = {st:2, st+1:2} except final step ({63:2})
      if (p == 7 && c == 7)
        asm volatile("s_waitcnt vmcnt(0) lgkmcnt(0)" ::: "memory");
      else
        asm volatile("s_waitcnt vmcnt(2) lgkmcnt(0)" ::: "memory");
      __builtin_amdgcn_s_barrier();
      __builtin_amdgcn_sched_barrier(0);
      const unsigned short* buf = &Wb[(p & 1) * 8192];
      if (p < 4) {
#pragma unroll
        for (int sl = 0; sl < 2; ++sl) {
          int k = p * 64 + sl * 32;
          bf16x8 af[4];
#pragma unroll
          for (int mi = 0; mi < 4; ++mi)
            af[mi] = *reinterpret_cast<const bf16x8*>(
                &buf[sl * 4096 + (wh1 + mi * 16 + l15) * 32 + rsw]);
          bf16x8 bx = *reinterpret_cast<const bf16x8*>(
              &xs[row1 * 256 + (((k >> 3) + quad) ^ sws) * 8]);
          __builtin_amdgcn_s_setprio(1);
#pragma unroll
          for (int mi = 0; mi < 4; ++mi)
            acc1[mi] = __builtin_amdgcn_mfma_f32_16x16x32_bf16(
                af[mi], bx, acc1[mi], 0, 0, 0);
          __builtin_amdgcn_s_setprio(0);
        }
        if (p == 3) {   // GELU + bias -> Hs (phase1 of chunk c complete)
#pragma unroll
          for (int mi = 0; mi < 4; ++mi) {
            int hb = wh1 + mi * 16 + quad * 4;
            float b0 = b1f[c * 128 + hb],      b1v = b1f[c * 128 + hb + 1];
            float b2v = b1f[c * 128 + hb + 2], b3 = b1f[c * 128 + hb + 3];
            ushort4 hw;
            hw.x = f2b(gelu_t(acc1[mi][0] + b0));
            hw.y = f2b(gelu_t(acc1[mi][1] + b1v));
            hw.z = f2b(gelu_t(acc1[mi][2] + b2v));
            hw.w = f2b(gelu_t(acc1[mi][3] + b3));
            *reinterpret_cast<ushort4*>(
                &Hs[row1 * 128 + (((hb >> 3) ^ sws) * 8) + (hb & 7)]) = hw;
          }
        }
      } else {
        int kk = (p - 4) * 32;
        bf16x8 af[2], bfr[4];
#pragma unroll
        for (int mi = 0; mi < 2; ++mi) {
          int hrow = wm2 + mi * 16 + l15;
          af[mi] = *reinterpret_cast<const bf16x8*>(
              &Hs[hrow * 128 + (((kk >> 3) + quad) ^ sws) * 8]);
        }
#pragma unroll
        for (int ni = 0; ni < 4; ++ni)
          bfr[ni] = *reinterpret_cast<const bf16x8*>(
              &buf[(wn2 + ni * 16 + l15) * 32 + rsw]);
        __builtin_amdgcn_s_setprio(1);
#pragma unroll
        for (int mi = 0; mi < 2; ++mi)
#pragma unroll
          for (int ni = 0; ni < 4; ++ni)
            acc[mi][ni] = __builtin_amdgcn_mfma_f32_16x16x32_bf16(
                af[mi], bfr[ni], acc[mi][ni], 0, 0, 0);
        __builtin_amdgcn_s_setprio(0);
      }
      __builtin_amdgcn_sched_barrier(0);
      __builtin_amdgcn_s_barrier();
      __builtin_amdgcn_sched_barrier(0);
      if (c < 7 || p < 6)
        stage_step((p + 2) & 7, p & 1);
    }
  }
  // ---- epilogue: out = resid + acc + b2 (fp32 RMW, thread-owned) ----
#pragma unroll
  for (int mi = 0; mi < 2; ++mi)
#pragma unroll
    for (int ni = 0; ni < 4; ++ni) {
      int col = wn2 + ni * 16 + l15;
      float bs = b2f[col];
#pragma unroll
      for (int r = 0; r < 4; ++r) {
        int g = bm + wm2 + mi * 16 + quad * 4 + r;
        size_t oi = (size_t)g * 256 + col;
        yio[oi] = yio[oi] + acc[mi][ni][r] + bs;
      }
    }
}

extern "C" void kernel_launch(void* const* d_in, const int* in_sizes, int n_in,
                              void* d_out, int out_size, void* d_ws, size_t ws_size,
                              hipStream_t stream) {
  const float* visual = (const float*)d_in[0];
  const float* text   = (const float*)d_in[1];
  const float* Wq  = (const float*)d_in[2];
  const float* bq  = (const float*)d_in[3];
  const float* Wk  = (const float*)d_in[4];
  const float* bk  = (const float*)d_in[5];
  const float* Wv  = (const float*)d_in[6];
  const float* bv  = (const float*)d_in[7];
  const float* Wo  = (const float*)d_in[8];
  const float* bo  = (const float*)d_in[9];
  const float* g1  = (const float*)d_in[10];
  const float* b1  = (const float*)d_in[11];
  const float* g2  = (const float*)d_in[12];
  const float* b2  = (const float*)d_in[13];
  const float* W1  = (const float*)d_in[14];
  const float* bf1 = (const float*)d_in[15];
  const float* W2  = (const float*)d_in[16];
  const float* bff2 = (const float*)d_in[17];
  const float* lsc = (const float*)d_in[18];
  const float* alp = (const float*)d_in[19];

  char* ws = (char*)d_ws;
  size_t off = 0;
  auto alloc = [&](size_t bytes) -> char* {
    char* p = ws + off;
    off += (bytes + 255) & ~(size_t)255;
    return p;
  };
  unsigned short* WqT = (unsigned short*)alloc((size_t)65536 * 2);
  unsigned short* WkT = (unsigned short*)alloc((size_t)131072 * 2);  // contiguous
  unsigned short* WvT = (unsigned short*)alloc((size_t)131072 * 2);  // with WkT
  unsigned short* WoT = (unsigned short*)alloc((size_t)65536 * 2);
  unsigned short* W1T = (unsigned short*)alloc((size_t)262144 * 2);
  unsigned short* W2T = (unsigned short*)alloc((size_t)262144 * 2);
  float*          bkv  = (float*)alloc(512 * 4);
  float*          kbuf = (float*)alloc((size_t)BT_ * CV_ * 4);
  float*          vbuf = (float*)alloc((size_t)BT_ * CV_ * 4);
  float*          padb = (float*)alloc((size_t)BT_ * 4);
  char* U = ws + off;                      // total ws ~= 36.3 MB
  unsigned short* xbuf = (unsigned short*)U;
  unsigned short* qbuf = (unsigned short*)(U + 16777216);
  float*          ybuf = (float*)d_out;

  // 1. prep: LN1 + LDS-tiled weight convT + kv bias + pad mask
  prep_kernel<<<8571, 256, 0, stream>>>(visual, g1, b1, xbuf,
                                        Wq, Wk, Wv, Wo, W1, W2,
                                        WqT, WkT, WvT, WoT, W1T, W2T,
                                        bk, bv, bkv, text, padb);
  // 2. q-proj + kv GEMM merged
  qkv_kernel<<<592, 256, 0, stream>>>(xbuf, WqT, bq, qbuf,
                                      text, WkT, bkv, kbuf, vbuf);
  // 3. attention v3: qbuf -> qbuf in place
  attn_kernel<<<dim3(64, NH_, NB), 256, 0, stream>>>(qbuf, kbuf, vbuf, padb, lsc);
  // 4. fused o-proj + residual + LN2: y bf16 (xbuf) + y fp32 (d_out)
  gemm_oln<<<512, 256, 0, stream>>>(qbuf, WoT, bo, xbuf, alp, g2, b2,
                                    xbuf, ybuf);
  // 5. fused FFN: 64-row tiles, 2 blocks/CU (reads y bf16 + fp32 resid RMW)
  ffn_fused<<<512, 512, 0, stream>>>(xbuf, W1T, bf1, W2T, bff2, ybuf);
}

// Round 11
// 274.935 us; speedup vs baseline: 1.0383x; 1.0024x over previous
//
#include <hip/hip_runtime.h>
#include <math.h>

// Problem constants
#define NB   8
#define NPIX 4096          // H*W
#define MROW 32768         // B*H*W
#define CV_  256
#define TT   77
#define CT_  512
#define NH_  8
#define DH_  32
#define BT_  616           // B*T

typedef __bf16 bf16x8 __attribute__((ext_vector_type(8)));
typedef float  f32x4  __attribute__((ext_vector_type(4)));

__device__ __forceinline__ float bf2f(unsigned short u) {
  return __uint_as_float(((unsigned)u) << 16);
}
__device__ __forceinline__ unsigned short f2b(float f) {
  unsigned u = __float_as_uint(f);
  return (unsigned short)((u + 0x7FFFu + ((u >> 16) & 1u)) >> 16);
}
__device__ __forceinline__ unsigned pack2(float lo, float hi) {
  return ((unsigned)f2b(hi) << 16) | (unsigned)f2b(lo);
}
__device__ __forceinline__ void async_copy16(const unsigned short* g,
                                             unsigned short* l) {
  __builtin_amdgcn_global_load_lds(
      (const __attribute__((address_space(1))) void*)g,
      (__attribute__((address_space(3))) void*)l, 16, 0, 0);
}
// tanh-GELU: 0.5*v*(1+tanh(0.79788456*(v+0.044715 v^3))) = v - v/(e^{2u}+1)
__device__ __forceinline__ float gelu_t(float v) {
  float p = v * fmaf(0.0713548162726f, v * v, 1.59576912161f);
  float e = __expf(p);
  return v - v / (e + 1.0f);
}

// -- prep: LN1 (0..8191) + LDS-tiled weight convT (8192..8415) +
//          kv bias (8416) + pad mask (8417..8570) --------------------------
__global__ __launch_bounds__(256) void prep_kernel(
    const float* __restrict__ visual, const float* __restrict__ g1,
    const float* __restrict__ b1, unsigned short* __restrict__ xbuf,
    const float* __restrict__ s0, const float* __restrict__ s1,
    const float* __restrict__ s2, const float* __restrict__ s3,
    const float* __restrict__ s4, const float* __restrict__ s5,
    unsigned short* __restrict__ d0, unsigned short* __restrict__ d1,
    unsigned short* __restrict__ d2, unsigned short* __restrict__ d3,
    unsigned short* __restrict__ d4, unsigned short* __restrict__ d5,
    const float* __restrict__ bk, const float* __restrict__ bv,
    float* __restrict__ bkv, const float* __restrict__ text,
    float* __restrict__ padb) {
  __shared__ unsigned short tl[64 * 68];   // 8704 B transpose tile
  int bx = blockIdx.x;
  int tid = threadIdx.x;
  int wave = tid >> 6, lane = tid & 63;
  if (bx < 8192) {                       // LN1: visual fp32 -> x bf16
    int row = bx * 4 + wave;
    size_t base = (size_t)row * 256 + lane * 4;
    float4 f = *reinterpret_cast<const float4*>(visual + base);
    float v0 = f.x, v1 = f.y, v2 = f.z, v3 = f.w;
    float s = v0 + v1 + v2 + v3;
    float q = v0 * v0 + v1 * v1 + v2 * v2 + v3 * v3;
#pragma unroll
    for (int off = 1; off < 64; off <<= 1) {
      s += __shfl_xor(s, off);
      q += __shfl_xor(q, off);
    }
    float mean = s * (1.0f / 256.0f);
    float var  = q * (1.0f / 256.0f) - mean * mean;
    float rstd = rsqrtf(var + 1e-5f);
    float4 gv = *reinterpret_cast<const float4*>(g1 + lane * 4);
    float4 bv4 = *reinterpret_cast<const float4*>(b1 + lane * 4);
    ushort4 o;
    o.x = f2b((v0 - mean) * rstd * gv.x + bv4.x);
    o.y = f2b((v1 - mean) * rstd * gv.y + bv4.y);
    o.z = f2b((v2 - mean) * rstd * gv.z + bv4.z);
    o.w = f2b((v3 - mean) * rstd * gv.w + bv4.w);
    *reinterpret_cast<ushort4*>(xbuf + base) = o;
    return;
  }
  if (bx < 8416) {                       // LDS-tiled 64x64 transpose
    int ti = bx - 8192;                  // 0..223
    const float* src; unsigned short* dst; int R, C, m;
    if      (ti < 16)  { src = s0; dst = d0; R = 256;  C = 256;  m = ti; }
    else if (ti < 48)  { src = s1; dst = d1; R = 512;  C = 256;  m = ti - 16; }
    else if (ti < 80)  { src = s2; dst = d2; R = 512;  C = 256;  m = ti - 48; }
    else if (ti < 96)  { src = s3; dst = d3; R = 256;  C = 256;  m = ti - 80; }
    else if (ti < 160) { src = s4; dst = d4; R = 256;  C = 1024; m = ti - 96; }
    else               { src = s5; dst = d5; R = 1024; C = 256;  m = ti - 160; }
    int tpc = C >> 6;
    int tr = m / tpc, tc = m % tpc;
#pragma unroll
    for (int i = 0; i < 4; ++i) {
      int lin = tid + i * 256;           // 0..1023
      int r = lin >> 4, c4 = (lin & 15) * 4;
      float4 f = *reinterpret_cast<const float4*>(
          src + (size_t)(tr * 64 + r) * C + tc * 64 + c4);
      tl[(c4 + 0) * 68 + r] = f2b(f.x);
      tl[(c4 + 1) * 68 + r] = f2b(f.y);
      tl[(c4 + 2) * 68 + r] = f2b(f.z);
      tl[(c4 + 3) * 68 + r] = f2b(f.w);
    }
    __syncthreads();
#pragma unroll
    for (int i = 0; i < 4; ++i) {
      int lin = tid + i * 256;
      int c = lin >> 4, r4 = (lin & 15) * 4;
      ushort4 u = *reinterpret_cast<const ushort4*>(&tl[c * 68 + r4]);
      *reinterpret_cast<ushort4*>(
          dst + (size_t)(tc * 64 + c) * R + tr * 64 + r4) = u;
    }
    return;
  }
  if (bx == 8416) {                      // kv bias concat
    bkv[tid] = bk[tid];
    bkv[256 + tid] = bv[tid];
    return;
  }
  {                                      // pad mask: one wave per (b,t) row
    int row = (bx - 8417) * 4 + wave;    // 0..615
    const float* tr = text + (size_t)row * CT_ + lane * 8;
    float4 f0 = *reinterpret_cast<const float4*>(tr);
    float4 f1 = *reinterpret_cast<const float4*>(tr + 4);
    float s = fabsf(f0.x) + fabsf(f0.y) + fabsf(f0.z) + fabsf(f0.w)
            + fabsf(f1.x) + fabsf(f1.y) + fabsf(f1.z) + fabsf(f1.w);
#pragma unroll
    for (int off = 1; off < 64; off <<= 1) s += __shfl_xor(s, off);
    if (lane == 0) padb[row] = (s <= 1e-6f) ? 1.0f : 0.0f;
  }
}

// ---- merged q-proj (blocks 0..1023, 128x64 tiles -> 4 blk/CU) +
//      kv GEMM (blocks 1024..1103) ----------------------------------------
__global__ __launch_bounds__(256) void qkv_kernel(
    const unsigned short* __restrict__ xb, const unsigned short* __restrict__ WqT,
    const float* __restrict__ bq, unsigned short* __restrict__ qout,
    const float* __restrict__ text, const unsigned short* __restrict__ WkvT,
    const float* __restrict__ bkv, float* __restrict__ kout,
    float* __restrict__ vout) {
  __shared__ unsigned short lA[4096];
  __shared__ unsigned short lB[4096];
  int tid = threadIdx.x;
  int lane = tid & 63, wave = tid >> 6;
  int l15 = lane & 15, quad = lane >> 4;
  if (blockIdx.x < 1024) {
    // ---- q-proj: 128x64 tile, K=256, m97 async staging ----
    int bm = (blockIdx.x >> 2) * 128, bn = (blockIdx.x & 3) * 64;
    int wm = (wave & 1) * 64, wn = (wave >> 1) * 32;
    int crow = lane >> 2, ccol = (lane & 3) * 8;
    f32x4 acc[4][2] = {};
    for (int k0 = 0; k0 < 256; k0 += 32) {
#pragma unroll
      for (int ch = 0; ch < 2; ++ch) {
        int c = wave * 2 + ch;
        async_copy16(xb + (size_t)(bm + c * 16 + crow) * 256 + k0 + ccol,
                     &lA[c * 512]);
      }
      async_copy16(WqT + (size_t)(bn + wave * 16 + crow) * 256 + k0 + ccol,
                   &lB[wave * 512]);
      __syncthreads();
      bf16x8 af[4], bfr[2];
#pragma unroll
      for (int mi = 0; mi < 4; ++mi)
        af[mi] = *reinterpret_cast<const bf16x8*>(&lA[(wm + mi * 16 + l15) * 32 + quad * 8]);
#pragma unroll
      for (int ni = 0; ni < 2; ++ni)
        bfr[ni] = *reinterpret_cast<const bf16x8*>(&lB[(wn + ni * 16 + l15) * 32 + quad * 8]);
#pragma unroll
      for (int mi = 0; mi < 4; ++mi)
#pragma unroll
        for (int ni = 0; ni < 2; ++ni)
          acc[mi][ni] = __builtin_amdgcn_mfma_f32_16x16x32_bf16(af[mi], bfr[ni],
                                                                acc[mi][ni], 0, 0, 0);
      __syncthreads();
    }
#pragma unroll
    for (int mi = 0; mi < 4; ++mi) {
#pragma unroll
      for (int ni = 0; ni < 2; ++ni) {
        int gcol = bn + wn + ni * 16 + l15;
        float bsf = bq[gcol];
#pragma unroll
        for (int r = 0; r < 4; ++r) {
          int grow = bm + wm + mi * 16 + quad * 4 + r;
          qout[(size_t)grow * 256 + gcol] = f2b(acc[mi][ni][r] + bsf);
        }
      }
    }
  } else {
    // ---- kv: 64x64 tile over (616, 512), K=512, fp32 A pack ----
    int i = blockIdx.x - 1024;
    int bm = (i % 10) * 64, bn = (i / 10) * 64;
    int srow = tid >> 2, sc8 = (tid & 3) * 8;
    int wm = (wave & 1) * 32, wn = (wave >> 1) * 32;
    f32x4 acc[2][2] = {};
    int gm = bm + srow, gn = bn + srow;
    const bool aok = (gm < BT_);
    for (int k0 = 0; k0 < CT_; k0 += 32) {
      uint4 apk = make_uint4(0, 0, 0, 0);
      if (aok) {
        const float* Af = text + (size_t)gm * CT_ + k0 + sc8;
        float4 f0 = *reinterpret_cast<const float4*>(Af);
        float4 f1 = *reinterpret_cast<const float4*>(Af + 4);
        apk.x = pack2(f0.x, f0.y); apk.y = pack2(f0.z, f0.w);
        apk.z = pack2(f1.x, f1.y); apk.w = pack2(f1.z, f1.w);
      }
      uint4 bpk = *reinterpret_cast<const uint4*>(WkvT + (size_t)gn * CT_ + k0 + sc8);
      *reinterpret_cast<uint4*>(&lA[srow * 40 + sc8]) = apk;
      *reinterpret_cast<uint4*>(&lB[srow * 40 + sc8]) = bpk;
      __syncthreads();
      bf16x8 a0 = *reinterpret_cast<const bf16x8*>(&lA[(wm + l15) * 40 + quad * 8]);
      bf16x8 a1 = *reinterpret_cast<const bf16x8*>(&lA[(wm + 16 + l15) * 40 + quad * 8]);
      bf16x8 b0 = *reinterpret_cast<const bf16x8*>(&lB[(wn + l15) * 40 + quad * 8]);
      bf16x8 b1 = *reinterpret_cast<const bf16x8*>(&lB[(wn + 16 + l15) * 40 + quad * 8]);
      acc[0][0] = __builtin_amdgcn_mfma_f32_16x16x32_bf16(a0, b0, acc[0][0], 0, 0, 0);
      acc[0][1] = __builtin_amdgcn_mfma_f32_16x16x32_bf16(a0, b1, acc[0][1], 0, 0, 0);
      acc[1][0] = __builtin_amdgcn_mfma_f32_16x16x32_bf16(a1, b0, acc[1][0], 0, 0, 0);
      acc[1][1] = __builtin_amdgcn_mfma_f32_16x16x32_bf16(a1, b1, acc[1][1], 0, 0, 0);
      __syncthreads();
    }
#pragma unroll
    for (int mt = 0; mt < 2; ++mt) {
#pragma unroll
      for (int nt = 0; nt < 2; ++nt) {
        int gcol = bn + wn + nt * 16 + l15;
        float bsf = bkv[gcol];
#pragma unroll
        for (int r = 0; r < 4; ++r) {
          int grow = bm + wm + mt * 16 + quad * 4 + r;
          if (grow >= BT_) continue;
          float v = acc[mt][nt][r] + bsf;
          if (gcol < 256) kout[(size_t)grow * 256 + gcol] = v;
          else            vout[(size_t)grow * 256 + gcol - 256] = v;
        }
      }
    }
  }
}

// ---- fused o-proj + residual + LN2 (32 rows/block, grid 1024 -> 4/CU) ----
__global__ __launch_bounds__(256) void gemm_oln(
    const unsigned short* __restrict__ A, const unsigned short* __restrict__ Bt,
    const float* __restrict__ bias, const unsigned short* __restrict__ xres,
    const float* __restrict__ alpha_ptr,
    const float* __restrict__ g2, const float* __restrict__ b2,
    unsigned short* __restrict__ ybf, float* __restrict__ yf32) {
  __shared__ unsigned short sm[9216];    // 18 KB: staging (9216) / yt (8192)
  unsigned short* lA = sm;               // 32x32 = 1024 shorts
  unsigned short* lB = sm + 1024;        // 256x32 = 8192 shorts
  unsigned short* yt = sm;               // 32x256 = 8192 shorts (aliased)
  const int K = 256;
  int tid = threadIdx.x;
  int bm = blockIdx.x * 32;
  int lane = tid & 63, wave = tid >> 6;
  int wm = (wave & 1) * 16, wn = (wave >> 1) * 128;
  int l15 = lane & 15, quad = lane >> 4;
  int crow = lane >> 2, ccol = (lane & 3) * 8;
  f32x4 acc[8] = {};
  for (int k0 = 0; k0 < K; k0 += 32) {
    if (wave < 2)
      async_copy16(A + (size_t)(bm + wave * 16 + crow) * K + k0 + ccol,
                   &lA[wave * 512]);
#pragma unroll
    for (int ch = wave; ch < 16; ch += 4)
      async_copy16(Bt + (size_t)(ch * 16 + crow) * K + k0 + ccol,
                   &lB[ch * 512]);
    __syncthreads();
    bf16x8 af, bfr[8];
    af = *reinterpret_cast<const bf16x8*>(&lA[(wm + l15) * 32 + quad * 8]);
#pragma unroll
    for (int ni = 0; ni < 8; ++ni)
      bfr[ni] = *reinterpret_cast<const bf16x8*>(&lB[(wn + ni * 16 + l15) * 32 + quad * 8]);
#pragma unroll
    for (int ni = 0; ni < 8; ++ni)
      acc[ni] = __builtin_amdgcn_mfma_f32_16x16x32_bf16(af, bfr[ni],
                                                        acc[ni], 0, 0, 0);
    __syncthreads();
  }
  float alpha = *alpha_ptr;
#pragma unroll
  for (int ni = 0; ni < 8; ++ni) {
    int gcol = wn + ni * 16 + l15;
    float bsf = bias[gcol];
#pragma unroll
    for (int r = 0; r < 4; ++r) {
      int lrow = wm + quad * 4 + r;
      float v = acc[ni][r] + bsf;
      float y0 = bf2f(xres[(size_t)(bm + lrow) * 256 + gcol]) + alpha * v;
      yt[lrow * 256 + gcol] = f2b(y0);
    }
  }
  __syncthreads();
  for (int it = 0; it < 8; ++it) {
    int row = wave * 8 + it;
    ushort4 u = *reinterpret_cast<const ushort4*>(&yt[row * 256 + lane * 4]);
    float v0 = bf2f(u.x), v1 = bf2f(u.y), v2 = bf2f(u.z), v3 = bf2f(u.w);
    float s = v0 + v1 + v2 + v3;
    float q = v0 * v0 + v1 * v1 + v2 * v2 + v3 * v3;
#pragma unroll
    for (int off = 1; off < 64; off <<= 1) {
      s += __shfl_xor(s, off);
      q += __shfl_xor(q, off);
    }
    float mean = s * (1.0f / 256.0f);
    float var  = q * (1.0f / 256.0f) - mean * mean;
    float rstd = rsqrtf(var + 1e-5f);
    float4 gv = *reinterpret_cast<const float4*>(g2 + lane * 4);
    float4 bv = *reinterpret_cast<const float4*>(b2 + lane * 4);
    float o0 = (v0 - mean) * rstd * gv.x + bv.x;
    float o1 = (v1 - mean) * rstd * gv.y + bv.y;
    float o2 = (v2 - mean) * rstd * gv.z + bv.z;
    float o3 = (v3 - mean) * rstd * gv.w + bv.w;
    size_t base = (size_t)(bm + row) * 256 + lane * 4;
    ushort4 ob;
    ob.x = f2b(o0); ob.y = f2b(o1); ob.z = f2b(o2); ob.w = f2b(o3);
    *reinterpret_cast<ushort4*>(ybf + base) = ob;
    *reinterpret_cast<float4*>(yf32 + base) = make_float4(o0, o1, o2, o3);
  }
}

// ---------- attention v3: MFMA QK^T + packed-index top-5 ------------------
#define SSTR 83
#define VSTR 33
#define NEGBIG -3.0e38f
__device__ __forceinline__ void ins5(float sv, float& tv0, float& tv1,
                                     float& tv2, float& tv3, float& tv4) {
  bool g0 = sv > tv0, g1 = sv > tv1, g2 = sv > tv2, g3 = sv > tv3, g4 = sv > tv4;
  tv4 = g4 ? (g3 ? tv3 : sv) : tv4;
  tv3 = g3 ? (g2 ? tv2 : sv) : tv3;
  tv2 = g2 ? (g1 ? tv1 : sv) : tv2;
  tv1 = g1 ? (g0 ? tv0 : sv) : tv1;
  tv0 = g0 ? sv : tv0;
}
__global__ __launch_bounds__(256) void attn_kernel(
    unsigned short* qa, const float* __restrict__ k,
    const float* __restrict__ v, const float* __restrict__ padb,
    const float* __restrict__ ls_ptr) {
  __shared__ unsigned short qb[64 * 40];
  __shared__ unsigned short kb[80 * 40];
  __shared__ float S[64 * SSTR];
  __shared__ float vs[TT * VSTR];
  __shared__ float rn[64];
  __shared__ float scs[80];
  __shared__ int allpad_s;
  int tid = threadIdx.x;
  int h = blockIdx.y, b = blockIdx.z;
  size_t qbase = ((size_t)b * NPIX + blockIdx.x * 64) * CV_ + h * DH_;
  size_t kvbase = (size_t)b * TT * CV_ + h * DH_;
  float ls = *ls_ptr;
  ls = fminf(fmaxf(ls, -2.0f), 2.0f);
  float scale = expf(ls) * 0.17677669529663687f;
  if (tid == 0) allpad_s = 1;
  __syncthreads();
  int qrow = tid >> 2, qq = tid & 3;
  uint4 qv4 = *reinterpret_cast<const uint4*>(qa + qbase + (size_t)qrow * CV_ + qq * 8);
  *reinterpret_cast<uint4*>(&qb[qrow * 40 + qq * 8]) = qv4;
  {
    float ssq = 0.f;
    unsigned w[4] = {qv4.x, qv4.y, qv4.z, qv4.w};
#pragma unroll
    for (int i = 0; i < 4; ++i) {
      float a = bf2f((unsigned short)(w[i] & 0xFFFF));
      float bb = bf2f((unsigned short)(w[i] >> 16));
      ssq += a * a + bb * bb;
    }
    ssq += __shfl_xor(ssq, 1);
    ssq += __shfl_xor(ssq, 2);
    if (qq == 0) rn[qrow] = scale / fmaxf(sqrtf(ssq), 1e-6f);
  }
  if (tid < 154) {
    int kr = tid >> 1, kh = tid & 1;
    const float* kp = k + kvbase + (size_t)kr * CV_ + kh * 16;
    float4 f0 = *reinterpret_cast<const float4*>(kp);
    float4 f1 = *reinterpret_cast<const float4*>(kp + 4);
    float4 f2 = *reinterpret_cast<const float4*>(kp + 8);
    float4 f3 = *reinterpret_cast<const float4*>(kp + 12);
    float ks2 = f0.x*f0.x + f0.y*f0.y + f0.z*f0.z + f0.w*f0.w
              + f1.x*f1.x + f1.y*f1.y + f1.z*f1.z + f1.w*f1.w
              + f2.x*f2.x + f2.y*f2.y + f2.z*f2.z + f2.w*f2.w
              + f3.x*f3.x + f3.y*f3.y + f3.z*f3.z + f3.w*f3.w;
    uint4 p0, p1;
    p0.x = pack2(f0.x, f0.y); p0.y = pack2(f0.z, f0.w);
    p0.z = pack2(f1.x, f1.y); p0.w = pack2(f1.z, f1.w);
    p1.x = pack2(f2.x, f2.y); p1.y = pack2(f2.z, f2.w);
    p1.z = pack2(f3.x, f3.y); p1.w = pack2(f3.z, f3.w);
    *reinterpret_cast<uint4*>(&kb[kr * 40 + kh * 16]) = p0;
    *reinterpret_cast<uint4*>(&kb[kr * 40 + kh * 16 + 8]) = p1;
    ks2 += __shfl_xor(ks2, 1);
    if (kh == 0) {
      float p = padb[b * TT + kr];
      float sc = (p == 0.0f) ? 1.0f / fmaxf(sqrtf(ks2), 1e-6f) : 0.0f;
      scs[kr] = sc;
      if (sc > 0.0f) allpad_s = 0;
    }
  } else if (tid < 157) {
    scs[77 + (tid - 154)] = 0.0f;
  } else if (tid >= 160 && tid < 172) {
    int i = tid - 160;
    *reinterpret_cast<uint4*>(&kb[(77 + (i >> 2)) * 40 + (i & 3) * 8]) =
        make_uint4(0, 0, 0, 0);
  }
  for (int j = tid; j < TT * 8; j += 256) {
    int t = j >> 3, d4 = j & 7;
    float4 f = *reinterpret_cast<const float4*>(
        v + kvbase + (size_t)t * CV_ + d4 * 4);
    float* vp = &vs[t * VSTR + d4 * 4];
    vp[0] = f.x; vp[1] = f.y; vp[2] = f.z; vp[3] = f.w;
  }
  __syncthreads();
  {
    int lane = tid & 63, wave = tid >> 6;
    int wm = wave * 16;
    int l15 = lane & 15, quad = lane >> 4;
    f32x4 acc[5] = {};
    bf16x8 af = *reinterpret_cast<const bf16x8*>(&qb[(wm + l15) * 40 + quad * 8]);
    bf16x8 bfr[5];
#pragma unroll
    for (int ni = 0; ni < 5; ++ni)
      bfr[ni] = *reinterpret_cast<const bf16x8*>(&kb[(ni * 16 + l15) * 40 + quad * 8]);
#pragma unroll
    for (int ni = 0; ni < 5; ++ni)
      acc[ni] = __builtin_amdgcn_mfma_f32_16x16x32_bf16(af, bfr[ni], acc[ni], 0, 0, 0);
#pragma unroll
    for (int ni = 0; ni < 5; ++ni) {
      int col = ni * 16 + l15;
      float sc = scs[col];
#pragma unroll
      for (int r = 0; r < 4; ++r) {
        int row = wm + quad * 4 + r;
        float val = (sc > 0.0f) ? acc[ni][r] * rn[row] * sc : NEGBIG;
        unsigned pb = (__float_as_uint(val) & 0xFFFFFF80u) | (unsigned)col;
        S[row * SSTR + col] = __uint_as_float(pb);
      }
    }
  }
  __syncthreads();
  int allpad = allpad_s;
  int row = qrow;
  const float* Srow = &S[row * SSTR];
  int t0 = qq * 20, t1 = (qq == 3) ? TT : t0 + 20;
  float tv0 = -INFINITY, tv1 = -INFINITY, tv2 = -INFINITY,
        tv3 = -INFINITY, tv4 = -INFINITY;
  for (int t = t0; t < t1; ++t)
    ins5(Srow[t], tv0, tv1, tv2, tv3, tv4);
#pragma unroll
  for (int m = 1; m <= 2; m <<= 1) {
    float n0 = __shfl_xor(tv0, m), n1 = __shfl_xor(tv1, m),
          n2 = __shfl_xor(tv2, m), n3 = __shfl_xor(tv3, m),
          n4 = __shfl_xor(tv4, m);
    ins5(n0, tv0, tv1, tv2, tv3, tv4);
    ins5(n1, tv0, tv1, tv2, tv3, tv4);
    ins5(n2, tv0, tv1, tv2, tv3, tv4);
    ins5(n3, tv0, tv1, tv2, tv3, tv4);
    ins5(n4, tv0, tv1, tv2, tv3, tv4);
  }
  float o[8];
#pragma unroll
  for (int d = 0; d < 8; ++d) o[d] = 0.f;
  if (!allpad) {
    float e0 = 1.0f;
    float e1 = expf(tv1 - tv0);
    float e2 = expf(tv2 - tv0);
    float e3 = expf(tv3 - tv0);
    float e4 = expf(tv4 - tv0);
    float inv = 1.0f / (e0 + e1 + e2 + e3 + e4);
    int i0 = __float_as_uint(tv0) & 0x7F, i1 = __float_as_uint(tv1) & 0x7F,
        i2 = __float_as_uint(tv2) & 0x7F, i3 = __float_as_uint(tv3) & 0x7F,
        i4 = __float_as_uint(tv4) & 0x7F;
    const float* v0p = &vs[i0 * VSTR + qq * 8];
    const float* v1p = &vs[i1 * VSTR + qq * 8];
    const float* v2p = &vs[i2 * VSTR + qq * 8];
    const float* v3p = &vs[i3 * VSTR + qq * 8];
    const float* v4p = &vs[i4 * VSTR + qq * 8];
#pragma unroll
    for (int d = 0; d < 8; ++d)
      o[d] = (e0 * v0p[d] + e1 * v1p[d] + e2 * v2p[d] + e3 * v3p[d] + e4 * v4p[d]) * inv;
  }
  unsigned short* qp = qa + qbase + (size_t)row * CV_ + qq * 8;
  uint4 ou;
  ou.x = ((unsigned)f2b(o[1]) << 16) | f2b(o[0]);
  ou.y = ((unsigned)f2b(o[3]) << 16) | f2b(o[2]);
  ou.z = ((unsigned)f2b(o[5]) << 16) | f2b(o[4]);
  ou.w = ((unsigned)f2b(o[7]) << 16) | f2b(o[6]);
  *reinterpret_cast<uint4*>(qp) = ou;
}

// ---------- fused FFN: out = y + gelu(y@W1+b1)@W2 + b2 -------------------
// R10-proven: 64-row tiles, 512 blocks = 2 blocks/CU, 8 waves, LDS 81920 B,
// 3-bit xs/Hs slot swizzle (phys slot = slot ^ (row&7)), Wb 2-bit swizzle,
// counted vmcnt(2), 2 raw s_barriers/step, setprio around MFMA.
__global__ __launch_bounds__(512) void ffn_fused(
    const unsigned short* __restrict__ ybf, const unsigned short* __restrict__ W1T,
    const float* __restrict__ b1f, const unsigned short* __restrict__ W2T,
    const float* __restrict__ b2f, float* __restrict__ yio) {
  __shared__ unsigned short xs[64 * 256];   // 32768 B, slot-swizzled (3-bit)
  __shared__ unsigned short Hs[64 * 128];   // 16384 B, slot-swizzled (3-bit)
  __shared__ unsigned short Wb[16384];      // 32 KB = 2 x 16KB halves
  int tid = threadIdx.x, lane = tid & 63, wave = tid >> 6;  // wave 0..7
  int l15 = lane & 15, quad = lane >> 4;
  int crow = lane >> 2;
  // Wb swizzle (R5-proven): slot(2b) ^= (row>>1)&3
  int ccs = (((lane & 3) ^ ((lane >> 3) & 3)) * 8);  // pre-swizzled global col
  int rsw = ((quad ^ ((l15 >> 1) & 3)) * 8);         // swizzled Wb read col
  int sws = l15 & 7;         // xs/Hs 3-bit row-swizzle (row bases 8-aligned)
  int bm = blockIdx.x * 64;
  {  // stage y-tile swizzled; 8 threads/row, 32 shorts each
    int row = tid >> 3, kh8 = (tid & 7) * 4;   // slot base (col/8)
    const unsigned short* src = ybf + (size_t)(bm + row) * 256 + kh8 * 8;
    int sw = row & 7;
    unsigned short* dst = &xs[row * 256];
#pragma unroll
    for (int i = 0; i < 4; ++i)
      *reinterpret_cast<uint4*>(dst + ((kh8 + i) ^ sw) * 8) =
          *reinterpret_cast<const uint4*>(src + i * 8);
  }
  int wm2 = (wave & 1) * 32, wn2 = (wave >> 1) * 64;   // phase2 tile
  int wh1 = (wave & 1) * 64, wr1 = (wave >> 1) * 16;   // phase1 tile
  int row1 = wr1 + l15;                                 // phase1 xs row
  // Running stage pointers (R8-proven, row-count independent):
  const unsigned short* w1p = W1T + (size_t)(wave * 16 + crow) * 256 + ccs;
  const unsigned short* w2p = W2T + (size_t)(wave * 32 + crow) * 1024 + ccs;
  auto stage_step = [&](int p2, int half) {
    unsigned short* buf = &Wb[half * 8192];
    if (p2 < 4) {
      async_copy16(w1p,      &buf[wave * 512]);
      async_copy16(w1p + 32, &buf[4096 + wave * 512]);
      w1p += 64;
      if (p2 == 3) w1p += 32512;         // next chunk: +32768 total
    } else {
      async_copy16(w2p,          &buf[wave * 1024]);
      async_copy16(w2p + 16384,  &buf[wave * 1024 + 512]);
      w2p += 32;                          // 4 steps = +128 = chunk stride
    }
  };
  f32x4 acc[2][4] = {};
  stage_step(0, 0); stage_step(1, 1);
  for (int c = 0; c < 8; ++c) {
    f32x4 acc1[4] = {};
#pragma unroll
    for (int p = 0; p < 8; ++p) {
      // ledger: outstanding = {st:2, st+1:2} except final step ({63:2})
      if (p == 7 && c == 7)
        asm volatile("s_waitcnt vmcnt(0) lgkmcnt(0)" ::: "memory");
      else
        asm volatile("s_waitcnt vmcnt(2) lgkmcnt(0)" ::: "memory");
      __builtin_amdgcn_s_barrier();
      __builtin_amdgcn_sched_barrier(0);
      const unsigned short* buf = &Wb[(p & 1) * 8192];
      if (p < 4) {
#pragma unroll
        for (int sl = 0; sl < 2; ++sl) {
          int k = p * 64 + sl * 32;
          bf16x8 af[4];
#pragma unroll
          for (int mi = 0; mi < 4; ++mi)
            af[mi] = *reinterpret_cast<const bf16x8*>(
                &buf[sl * 4096 + (wh1 + mi * 16 + l15) * 32 + rsw]);
          bf16x8 bx = *reinterpret_cast<const bf16x8*>(
              &xs[row1 * 256 + (((k >> 3) + quad) ^ sws) * 8]);
          __builtin_amdgcn_s_setprio(1);
#pragma unroll
          for (int mi = 0; mi < 4; ++mi)
            acc1[mi] = __builtin_amdgcn_mfma_f32_16x16x32_bf16(
                af[mi], bx, acc1[mi], 0, 0, 0);
          __builtin_amdgcn_s_setprio(0);
        }
        if (p == 3) {   // GELU + bias -> Hs (phase1 of chunk c complete)
#pragma unroll
          for (int mi = 0; mi < 4; ++mi) {
            int hb = wh1 + mi * 16 + quad * 4;
            float b0 = b1f[c * 128 + hb],      b1v = b1f[c * 128 + hb + 1];
            float b2v = b1f[c * 128 + hb + 2], b3 = b1f[c * 128 + hb + 3];
            ushort4 hw;
            hw.x = f2b(gelu_t(acc1[mi][0] + b0));
            hw.y = f2b(gelu_t(acc1[mi][1] + b1v));
            hw.z = f2b(gelu_t(acc1[mi][2] + b2v));
            hw.w = f2b(gelu_t(acc1[mi][3] + b3));
            *reinterpret_cast<ushort4*>(
                &Hs[row1 * 128 + (((hb >> 3) ^ sws) * 8) + (hb & 7)]) = hw;
          }
        }
      } else {
        int kk = (p - 4) * 32;
        bf16x8 af[2], bfr[4];
#pragma unroll
        for (int mi = 0; mi < 2; ++mi) {
          int hrow = wm2 + mi * 16 + l15;
          af[mi] = *reinterpret_cast<const bf16x8*>(
              &Hs[hrow * 128 + (((kk >> 3) + quad) ^ sws) * 8]);
        }
#pragma unroll
        for (int ni = 0; ni < 4; ++ni)
          bfr[ni] = *reinterpret_cast<const bf16x8*>(
              &buf[(wn2 + ni * 16 + l15) * 32 + rsw]);
        __builtin_amdgcn_s_setprio(1);
#pragma unroll
        for (int mi = 0; mi < 2; ++mi)
#pragma unroll
          for (int ni = 0; ni < 4; ++ni)
            acc[mi][ni] = __builtin_amdgcn_mfma_f32_16x16x32_bf16(
                af[mi], bfr[ni], acc[mi][ni], 0, 0, 0);
        __builtin_amdgcn_s_setprio(0);
      }
      __builtin_amdgcn_sched_barrier(0);
      __builtin_amdgcn_s_barrier();
      __builtin_amdgcn_sched_barrier(0);
      if (c < 7 || p < 6)
        stage_step((p + 2) & 7, p & 1);
    }
  }
  // ---- epilogue: out = resid + acc + b2 (fp32 RMW, thread-owned) ----
#pragma unroll
  for (int mi = 0; mi < 2; ++mi)
#pragma unroll
    for (int ni = 0; ni < 4; ++ni) {
      int col = wn2 + ni * 16 + l15;
      float bs = b2f[col];
#pragma unroll
      for (int r = 0; r < 4; ++r) {
        int g = bm + wm2 + mi * 16 + quad * 4 + r;
        size_t oi = (size_t)g * 256 + col;
        yio[oi] = yio[oi] + acc[mi][ni][r] + bs;
      }
    }
}

extern "C" void kernel_launch(void* const* d_in, const int* in_sizes, int n_in,
                              void* d_out, int out_size, void* d_ws, size_t ws_size,
                              hipStream_t stream) {
  const float* visual = (const float*)d_in[0];
  const float* text   = (const float*)d_in[1];
  const float* Wq  = (const float*)d_in[2];
  const float* bq  = (const float*)d_in[3];
  const float* Wk  = (const float*)d_in[4];
  const float* bk  = (const float*)d_in[5];
  const float* Wv  = (const float*)d_in[6];
  const float* bv  = (const float*)d_in[7];
  const float* Wo  = (const float*)d_in[8];
  const float* bo  = (const float*)d_in[9];
  const float* g1  = (const float*)d_in[10];
  const float* b1  = (const float*)d_in[11];
  const float* g2  = (const float*)d_in[12];
  const float* b2  = (const float*)d_in[13];
  const float* W1  = (const float*)d_in[14];
  const float* bf1 = (const float*)d_in[15];
  const float* W2  = (const float*)d_in[16];
  const float* bff2 = (const float*)d_in[17];
  const float* lsc = (const float*)d_in[18];
  const float* alp = (const float*)d_in[19];

  char* ws = (char*)d_ws;
  size_t off = 0;
  auto alloc = [&](size_t bytes) -> char* {
    char* p = ws + off;
    off += (bytes + 255) & ~(size_t)255;
    return p;
  };
  unsigned short* WqT = (unsigned short*)alloc((size_t)65536 * 2);
  unsigned short* WkT = (unsigned short*)alloc((size_t)131072 * 2);  // contiguous
  unsigned short* WvT = (unsigned short*)alloc((size_t)131072 * 2);  // with WkT
  unsigned short* WoT = (unsigned short*)alloc((size_t)65536 * 2);
  unsigned short* W1T = (unsigned short*)alloc((size_t)262144 * 2);
  unsigned short* W2T = (unsigned short*)alloc((size_t)262144 * 2);
  float*          bkv  = (float*)alloc(512 * 4);
  float*          kbuf = (float*)alloc((size_t)BT_ * CV_ * 4);
  float*          vbuf = (float*)alloc((size_t)BT_ * CV_ * 4);
  float*          padb = (float*)alloc((size_t)BT_ * 4);
  char* U = ws + off;                      // total ws ~= 36.3 MB
  unsigned short* xbuf = (unsigned short*)U;
  unsigned short* qbuf = (unsigned short*)(U + 16777216);
  float*          ybuf = (float*)d_out;

  // 1. prep: LN1 + LDS-tiled weight convT + kv bias + pad mask
  prep_kernel<<<8571, 256, 0, stream>>>(visual, g1, b1, xbuf,
                                        Wq, Wk, Wv, Wo, W1, W2,
                                        WqT, WkT, WvT, WoT, W1T, W2T,
                                        bk, bv, bkv, text, padb);
  // 2. q-proj (128x64 tiles, 4 blk/CU) + kv GEMM merged
  qkv_kernel<<<1104, 256, 0, stream>>>(xbuf, WqT, bq, qbuf,
                                       text, WkT, bkv, kbuf, vbuf);
  // 3. attention v3: qbuf -> qbuf in place
  attn_kernel<<<dim3(64, NH_, NB), 256, 0, stream>>>(qbuf, kbuf, vbuf, padb, lsc);
  // 4. fused o-proj + residual + LN2 (32 rows, 4 blk/CU)
  gemm_oln<<<1024, 256, 0, stream>>>(qbuf, WoT, bo, xbuf, alp, g2, b2,
                                     xbuf, ybuf);
  // 5. fused FFN: 64-row tiles, 2 blocks/CU (reads y bf16 + fp32 resid RMW)
  ffn_fused<<<512, 512, 0, stream>>>(xbuf, W1T, bf1, W2T, bff2, ybuf);
}

// Round 12
// 263.029 us; speedup vs baseline: 1.0853x; 1.0453x over previous
//
#include <hip/hip_runtime.h>
#include <math.h>

// Problem constants
#define NB   8
#define NPIX 4096          // H*W
#define MROW 32768         // B*H*W
#define CV_  256
#define TT   77
#define CT_  512
#define NH_  8
#define DH_  32
#define BT_  616           // B*T

typedef __bf16 bf16x8 __attribute__((ext_vector_type(8)));
typedef float  f32x4  __attribute__((ext_vector_type(4)));

__device__ __forceinline__ float bf2f(unsigned short u) {
  return __uint_as_float(((unsigned)u) << 16);
}
__device__ __forceinline__ unsigned short f2b(float f) {
  unsigned u = __float_as_uint(f);
  return (unsigned short)((u + 0x7FFFu + ((u >> 16) & 1u)) >> 16);
}
__device__ __forceinline__ unsigned pack2(float lo, float hi) {
  return ((unsigned)f2b(hi) << 16) | (unsigned)f2b(lo);
}
__device__ __forceinline__ void async_copy16(const unsigned short* g,
                                             unsigned short* l) {
  __builtin_amdgcn_global_load_lds(
      (const __attribute__((address_space(1))) void*)g,
      (__attribute__((address_space(3))) void*)l, 16, 0, 0);
}
// tanh-GELU: 0.5*v*(1+tanh(0.79788456*(v+0.044715 v^3))) = v - v/(e^{2u}+1)
__device__ __forceinline__ float gelu_t(float v) {
  float p = v * fmaf(0.0713548162726f, v * v, 1.59576912161f);
  float e = __expf(p);
  return v - v / (e + 1.0f);
}

// -- prep: LN1 (0..8191) + LDS-tiled weight convT (8192..8415) +
//          kv bias (8416) + pad mask (8417..8570) --------------------------
__global__ __launch_bounds__(256) void prep_kernel(
    const float* __restrict__ visual, const float* __restrict__ g1,
    const float* __restrict__ b1, unsigned short* __restrict__ xbuf,
    const float* __restrict__ s0, const float* __restrict__ s1,
    const float* __restrict__ s2, const float* __restrict__ s3,
    const float* __restrict__ s4, const float* __restrict__ s5,
    unsigned short* __restrict__ d0, unsigned short* __restrict__ d1,
    unsigned short* __restrict__ d2, unsigned short* __restrict__ d3,
    unsigned short* __restrict__ d4, unsigned short* __restrict__ d5,
    const float* __restrict__ bk, const float* __restrict__ bv,
    float* __restrict__ bkv, const float* __restrict__ text,
    float* __restrict__ padb) {
  __shared__ unsigned short tl[64 * 68];   // 8704 B transpose tile
  int bx = blockIdx.x;
  int tid = threadIdx.x;
  int wave = tid >> 6, lane = tid & 63;
  if (bx < 8192) {                       // LN1: visual fp32 -> x bf16
    int row = bx * 4 + wave;
    size_t base = (size_t)row * 256 + lane * 4;
    float4 f = *reinterpret_cast<const float4*>(visual + base);
    float v0 = f.x, v1 = f.y, v2 = f.z, v3 = f.w;
    float s = v0 + v1 + v2 + v3;
    float q = v0 * v0 + v1 * v1 + v2 * v2 + v3 * v3;
#pragma unroll
    for (int off = 1; off < 64; off <<= 1) {
      s += __shfl_xor(s, off);
      q += __shfl_xor(q, off);
    }
    float mean = s * (1.0f / 256.0f);
    float var  = q * (1.0f / 256.0f) - mean * mean;
    float rstd = rsqrtf(var + 1e-5f);
    float4 gv = *reinterpret_cast<const float4*>(g1 + lane * 4);
    float4 bv4 = *reinterpret_cast<const float4*>(b1 + lane * 4);
    ushort4 o;
    o.x = f2b((v0 - mean) * rstd * gv.x + bv4.x);
    o.y = f2b((v1 - mean) * rstd * gv.y + bv4.y);
    o.z = f2b((v2 - mean) * rstd * gv.z + bv4.z);
    o.w = f2b((v3 - mean) * rstd * gv.w + bv4.w);
    *reinterpret_cast<ushort4*>(xbuf + base) = o;
    return;
  }
  if (bx < 8416) {                       // LDS-tiled 64x64 transpose
    int ti = bx - 8192;                  // 0..223
    const float* src; unsigned short* dst; int R, C, m;
    if      (ti < 16)  { src = s0; dst = d0; R = 256;  C = 256;  m = ti; }
    else if (ti < 48)  { src = s1; dst = d1; R = 512;  C = 256;  m = ti - 16; }
    else if (ti < 80)  { src = s2; dst = d2; R = 512;  C = 256;  m = ti - 48; }
    else if (ti < 96)  { src = s3; dst = d3; R = 256;  C = 256;  m = ti - 80; }
    else if (ti < 160) { src = s4; dst = d4; R = 256;  C = 1024; m = ti - 96; }
    else               { src = s5; dst = d5; R = 1024; C = 256;  m = ti - 160; }
    int tpc = C >> 6;
    int tr = m / tpc, tc = m % tpc;
#pragma unroll
    for (int i = 0; i < 4; ++i) {
      int lin = tid + i * 256;           // 0..1023
      int r = lin >> 4, c4 = (lin & 15) * 4;
      float4 f = *reinterpret_cast<const float4*>(
          src + (size_t)(tr * 64 + r) * C + tc * 64 + c4);
      tl[(c4 + 0) * 68 + r] = f2b(f.x);
      tl[(c4 + 1) * 68 + r] = f2b(f.y);
      tl[(c4 + 2) * 68 + r] = f2b(f.z);
      tl[(c4 + 3) * 68 + r] = f2b(f.w);
    }
    __syncthreads();
#pragma unroll
    for (int i = 0; i < 4; ++i) {
      int lin = tid + i * 256;
      int c = lin >> 4, r4 = (lin & 15) * 4;
      ushort4 u = *reinterpret_cast<const ushort4*>(&tl[c * 68 + r4]);
      *reinterpret_cast<ushort4*>(
          dst + (size_t)(tc * 64 + c) * R + tr * 64 + r4) = u;
    }
    return;
  }
  if (bx == 8416) {                      // kv bias concat
    bkv[tid] = bk[tid];
    bkv[256 + tid] = bv[tid];
    return;
  }
  {                                      // pad mask: one wave per (b,t) row
    int row = (bx - 8417) * 4 + wave;    // 0..615
    const float* tr = text + (size_t)row * CT_ + lane * 8;
    float4 f0 = *reinterpret_cast<const float4*>(tr);
    float4 f1 = *reinterpret_cast<const float4*>(tr + 4);
    float s = fabsf(f0.x) + fabsf(f0.y) + fabsf(f0.z) + fabsf(f0.w)
            + fabsf(f1.x) + fabsf(f1.y) + fabsf(f1.z) + fabsf(f1.w);
#pragma unroll
    for (int off = 1; off < 64; off <<= 1) s += __shfl_xor(s, off);
    if (lane == 0) padb[row] = (s <= 1e-6f) ? 1.0f : 0.0f;
  }
}

// ---- merged q-proj (blocks 0..1023, 128x64 tiles -> 4 blk/CU) +
//      kv GEMM (blocks 1024..1103) ----------------------------------------
__global__ __launch_bounds__(256) void qkv_kernel(
    const unsigned short* __restrict__ xb, const unsigned short* __restrict__ WqT,
    const float* __restrict__ bq, unsigned short* __restrict__ qout,
    const float* __restrict__ text, const unsigned short* __restrict__ WkvT,
    const float* __restrict__ bkv, float* __restrict__ kout,
    float* __restrict__ vout) {
  __shared__ unsigned short lA[4096];
  __shared__ unsigned short lB[4096];
  int tid = threadIdx.x;
  int lane = tid & 63, wave = tid >> 6;
  int l15 = lane & 15, quad = lane >> 4;
  if (blockIdx.x < 1024) {
    // ---- q-proj: 128x64 tile, K=256, m97 async staging ----
    int bm = (blockIdx.x >> 2) * 128, bn = (blockIdx.x & 3) * 64;
    int wm = (wave & 1) * 64, wn = (wave >> 1) * 32;
    int crow = lane >> 2, ccol = (lane & 3) * 8;
    f32x4 acc[4][2] = {};
    for (int k0 = 0; k0 < 256; k0 += 32) {
#pragma unroll
      for (int ch = 0; ch < 2; ++ch) {
        int c = wave * 2 + ch;
        async_copy16(xb + (size_t)(bm + c * 16 + crow) * 256 + k0 + ccol,
                     &lA[c * 512]);
      }
      async_copy16(WqT + (size_t)(bn + wave * 16 + crow) * 256 + k0 + ccol,
                   &lB[wave * 512]);
      __syncthreads();
      bf16x8 af[4], bfr[2];
#pragma unroll
      for (int mi = 0; mi < 4; ++mi)
        af[mi] = *reinterpret_cast<const bf16x8*>(&lA[(wm + mi * 16 + l15) * 32 + quad * 8]);
#pragma unroll
      for (int ni = 0; ni < 2; ++ni)
        bfr[ni] = *reinterpret_cast<const bf16x8*>(&lB[(wn + ni * 16 + l15) * 32 + quad * 8]);
#pragma unroll
      for (int mi = 0; mi < 4; ++mi)
#pragma unroll
        for (int ni = 0; ni < 2; ++ni)
          acc[mi][ni] = __builtin_amdgcn_mfma_f32_16x16x32_bf16(af[mi], bfr[ni],
                                                                acc[mi][ni], 0, 0, 0);
      __syncthreads();
    }
#pragma unroll
    for (int mi = 0; mi < 4; ++mi) {
#pragma unroll
      for (int ni = 0; ni < 2; ++ni) {
        int gcol = bn + wn + ni * 16 + l15;
        float bsf = bq[gcol];
#pragma unroll
        for (int r = 0; r < 4; ++r) {
          int grow = bm + wm + mi * 16 + quad * 4 + r;
          qout[(size_t)grow * 256 + gcol] = f2b(acc[mi][ni][r] + bsf);
        }
      }
    }
  } else {
    // ---- kv: 64x64 tile over (616, 512), K=512, fp32 A pack ----
    int i = blockIdx.x - 1024;
    int bm = (i % 10) * 64, bn = (i / 10) * 64;
    int srow = tid >> 2, sc8 = (tid & 3) * 8;
    int wm = (wave & 1) * 32, wn = (wave >> 1) * 32;
    f32x4 acc[2][2] = {};
    int gm = bm + srow, gn = bn + srow;
    const bool aok = (gm < BT_);
    for (int k0 = 0; k0 < CT_; k0 += 32) {
      uint4 apk = make_uint4(0, 0, 0, 0);
      if (aok) {
        const float* Af = text + (size_t)gm * CT_ + k0 + sc8;
        float4 f0 = *reinterpret_cast<const float4*>(Af);
        float4 f1 = *reinterpret_cast<const float4*>(Af + 4);
        apk.x = pack2(f0.x, f0.y); apk.y = pack2(f0.z, f0.w);
        apk.z = pack2(f1.x, f1.y); apk.w = pack2(f1.z, f1.w);
      }
      uint4 bpk = *reinterpret_cast<const uint4*>(WkvT + (size_t)gn * CT_ + k0 + sc8);
      *reinterpret_cast<uint4*>(&lA[srow * 40 + sc8]) = apk;
      *reinterpret_cast<uint4*>(&lB[srow * 40 + sc8]) = bpk;
      __syncthreads();
      bf16x8 a0 = *reinterpret_cast<const bf16x8*>(&lA[(wm + l15) * 40 + quad * 8]);
      bf16x8 a1 = *reinterpret_cast<const bf16x8*>(&lA[(wm + 16 + l15) * 40 + quad * 8]);
      bf16x8 b0 = *reinterpret_cast<const bf16x8*>(&lB[(wn + l15) * 40 + quad * 8]);
      bf16x8 b1 = *reinterpret_cast<const bf16x8*>(&lB[(wn + 16 + l15) * 40 + quad * 8]);
      acc[0][0] = __builtin_amdgcn_mfma_f32_16x16x32_bf16(a0, b0, acc[0][0], 0, 0, 0);
      acc[0][1] = __builtin_amdgcn_mfma_f32_16x16x32_bf16(a0, b1, acc[0][1], 0, 0, 0);
      acc[1][0] = __builtin_amdgcn_mfma_f32_16x16x32_bf16(a1, b0, acc[1][0], 0, 0, 0);
      acc[1][1] = __builtin_amdgcn_mfma_f32_16x16x32_bf16(a1, b1, acc[1][1], 0, 0, 0);
      __syncthreads();
    }
#pragma unroll
    for (int mt = 0; mt < 2; ++mt) {
#pragma unroll
      for (int nt = 0; nt < 2; ++nt) {
        int gcol = bn + wn + nt * 16 + l15;
        float bsf = bkv[gcol];
#pragma unroll
        for (int r = 0; r < 4; ++r) {
          int grow = bm + wm + mt * 16 + quad * 4 + r;
          if (grow >= BT_) continue;
          float v = acc[mt][nt][r] + bsf;
          if (gcol < 256) kout[(size_t)grow * 256 + gcol] = v;
          else            vout[(size_t)grow * 256 + gcol - 256] = v;
        }
      }
    }
  }
}

// ---------- attention v3: MFMA QK^T + packed-index top-5 ------------------
#define SSTR 83
#define VSTR 33
#define NEGBIG -3.0e38f
__device__ __forceinline__ void ins5(float sv, float& tv0, float& tv1,
                                     float& tv2, float& tv3, float& tv4) {
  bool g0 = sv > tv0, g1 = sv > tv1, g2 = sv > tv2, g3 = sv > tv3, g4 = sv > tv4;
  tv4 = g4 ? (g3 ? tv3 : sv) : tv4;
  tv3 = g3 ? (g2 ? tv2 : sv) : tv3;
  tv2 = g2 ? (g1 ? tv1 : sv) : tv2;
  tv1 = g1 ? (g0 ? tv0 : sv) : tv1;
  tv0 = g0 ? sv : tv0;
}
__global__ __launch_bounds__(256) void attn_kernel(
    unsigned short* qa, const float* __restrict__ k,
    const float* __restrict__ v, const float* __restrict__ padb,
    const float* __restrict__ ls_ptr) {
  __shared__ unsigned short qb[64 * 40];
  __shared__ unsigned short kb[80 * 40];
  __shared__ float S[64 * SSTR];
  __shared__ float vs[TT * VSTR];
  __shared__ float rn[64];
  __shared__ float scs[80];
  __shared__ int allpad_s;
  int tid = threadIdx.x;
  int h = blockIdx.y, b = blockIdx.z;
  size_t qbase = ((size_t)b * NPIX + blockIdx.x * 64) * CV_ + h * DH_;
  size_t kvbase = (size_t)b * TT * CV_ + h * DH_;
  float ls = *ls_ptr;
  ls = fminf(fmaxf(ls, -2.0f), 2.0f);
  float scale = expf(ls) * 0.17677669529663687f;
  if (tid == 0) allpad_s = 1;
  __syncthreads();
  int qrow = tid >> 2, qq = tid & 3;
  uint4 qv4 = *reinterpret_cast<const uint4*>(qa + qbase + (size_t)qrow * CV_ + qq * 8);
  *reinterpret_cast<uint4*>(&qb[qrow * 40 + qq * 8]) = qv4;
  {
    float ssq = 0.f;
    unsigned w[4] = {qv4.x, qv4.y, qv4.z, qv4.w};
#pragma unroll
    for (int i = 0; i < 4; ++i) {
      float a = bf2f((unsigned short)(w[i] & 0xFFFF));
      float bb = bf2f((unsigned short)(w[i] >> 16));
      ssq += a * a + bb * bb;
    }
    ssq += __shfl_xor(ssq, 1);
    ssq += __shfl_xor(ssq, 2);
    if (qq == 0) rn[qrow] = scale / fmaxf(sqrtf(ssq), 1e-6f);
  }
  if (tid < 154) {
    int kr = tid >> 1, kh = tid & 1;
    const float* kp = k + kvbase + (size_t)kr * CV_ + kh * 16;
    float4 f0 = *reinterpret_cast<const float4*>(kp);
    float4 f1 = *reinterpret_cast<const float4*>(kp + 4);
    float4 f2 = *reinterpret_cast<const float4*>(kp + 8);
    float4 f3 = *reinterpret_cast<const float4*>(kp + 12);
    float ks2 = f0.x*f0.x + f0.y*f0.y + f0.z*f0.z + f0.w*f0.w
              + f1.x*f1.x + f1.y*f1.y + f1.z*f1.z + f1.w*f1.w
              + f2.x*f2.x + f2.y*f2.y + f2.z*f2.z + f2.w*f2.w
              + f3.x*f3.x + f3.y*f3.y + f3.z*f3.z + f3.w*f3.w;
    uint4 p0, p1;
    p0.x = pack2(f0.x, f0.y); p0.y = pack2(f0.z, f0.w);
    p0.z = pack2(f1.x, f1.y); p0.w = pack2(f1.z, f1.w);
    p1.x = pack2(f2.x, f2.y); p1.y = pack2(f2.z, f2.w);
    p1.z = pack2(f3.x, f3.y); p1.w = pack2(f3.z, f3.w);
    *reinterpret_cast<uint4*>(&kb[kr * 40 + kh * 16]) = p0;
    *reinterpret_cast<uint4*>(&kb[kr * 40 + kh * 16 + 8]) = p1;
    ks2 += __shfl_xor(ks2, 1);
    if (kh == 0) {
      float p = padb[b * TT + kr];
      float sc = (p == 0.0f) ? 1.0f / fmaxf(sqrtf(ks2), 1e-6f) : 0.0f;
      scs[kr] = sc;
      if (sc > 0.0f) allpad_s = 0;
    }
  } else if (tid < 157) {
    scs[77 + (tid - 154)] = 0.0f;
  } else if (tid >= 160 && tid < 172) {
    int i = tid - 160;
    *reinterpret_cast<uint4*>(&kb[(77 + (i >> 2)) * 40 + (i & 3) * 8]) =
        make_uint4(0, 0, 0, 0);
  }
  for (int j = tid; j < TT * 8; j += 256) {
    int t = j >> 3, d4 = j & 7;
    float4 f = *reinterpret_cast<const float4*>(
        v + kvbase + (size_t)t * CV_ + d4 * 4);
    float* vp = &vs[t * VSTR + d4 * 4];
    vp[0] = f.x; vp[1] = f.y; vp[2] = f.z; vp[3] = f.w;
  }
  __syncthreads();
  {
    int lane = tid & 63, wave = tid >> 6;
    int wm = wave * 16;
    int l15 = lane & 15, quad = lane >> 4;
    f32x4 acc[5] = {};
    bf16x8 af = *reinterpret_cast<const bf16x8*>(&qb[(wm + l15) * 40 + quad * 8]);
    bf16x8 bfr[5];
#pragma unroll
    for (int ni = 0; ni < 5; ++ni)
      bfr[ni] = *reinterpret_cast<const bf16x8*>(&kb[(ni * 16 + l15) * 40 + quad * 8]);
#pragma unroll
    for (int ni = 0; ni < 5; ++ni)
      acc[ni] = __builtin_amdgcn_mfma_f32_16x16x32_bf16(af, bfr[ni], acc[ni], 0, 0, 0);
#pragma unroll
    for (int ni = 0; ni < 5; ++ni) {
      int col = ni * 16 + l15;
      float sc = scs[col];
#pragma unroll
      for (int r = 0; r < 4; ++r) {
        int row = wm + quad * 4 + r;
        float val = (sc > 0.0f) ? acc[ni][r] * rn[row] * sc : NEGBIG;
        unsigned pb = (__float_as_uint(val) & 0xFFFFFF80u) | (unsigned)col;
        S[row * SSTR + col] = __uint_as_float(pb);
      }
    }
  }
  __syncthreads();
  int allpad = allpad_s;
  int row = qrow;
  const float* Srow = &S[row * SSTR];
  int t0 = qq * 20, t1 = (qq == 3) ? TT : t0 + 20;
  float tv0 = -INFINITY, tv1 = -INFINITY, tv2 = -INFINITY,
        tv3 = -INFINITY, tv4 = -INFINITY;
  for (int t = t0; t < t1; ++t)
    ins5(Srow[t], tv0, tv1, tv2, tv3, tv4);
#pragma unroll
  for (int m = 1; m <= 2; m <<= 1) {
    float n0 = __shfl_xor(tv0, m), n1 = __shfl_xor(tv1, m),
          n2 = __shfl_xor(tv2, m), n3 = __shfl_xor(tv3, m),
          n4 = __shfl_xor(tv4, m);
    ins5(n0, tv0, tv1, tv2, tv3, tv4);
    ins5(n1, tv0, tv1, tv2, tv3, tv4);
    ins5(n2, tv0, tv1, tv2, tv3, tv4);
    ins5(n3, tv0, tv1, tv2, tv3, tv4);
    ins5(n4, tv0, tv1, tv2, tv3, tv4);
  }
  float o[8];
#pragma unroll
  for (int d = 0; d < 8; ++d) o[d] = 0.f;
  if (!allpad) {
    float e0 = 1.0f;
    float e1 = expf(tv1 - tv0);
    float e2 = expf(tv2 - tv0);
    float e3 = expf(tv3 - tv0);
    float e4 = expf(tv4 - tv0);
    float inv = 1.0f / (e0 + e1 + e2 + e3 + e4);
    int i0 = __float_as_uint(tv0) & 0x7F, i1 = __float_as_uint(tv1) & 0x7F,
        i2 = __float_as_uint(tv2) & 0x7F, i3 = __float_as_uint(tv3) & 0x7F,
        i4 = __float_as_uint(tv4) & 0x7F;
    const float* v0p = &vs[i0 * VSTR + qq * 8];
    const float* v1p = &vs[i1 * VSTR + qq * 8];
    const float* v2p = &vs[i2 * VSTR + qq * 8];
    const float* v3p = &vs[i3 * VSTR + qq * 8];
    const float* v4p = &vs[i4 * VSTR + qq * 8];
#pragma unroll
    for (int d = 0; d < 8; ++d)
      o[d] = (e0 * v0p[d] + e1 * v1p[d] + e2 * v2p[d] + e3 * v3p[d] + e4 * v4p[d]) * inv;
  }
  unsigned short* qp = qa + qbase + (size_t)row * CV_ + qq * 8;
  uint4 ou;
  ou.x = ((unsigned)f2b(o[1]) << 16) | f2b(o[0]);
  ou.y = ((unsigned)f2b(o[3]) << 16) | f2b(o[2]);
  ou.z = ((unsigned)f2b(o[5]) << 16) | f2b(o[4]);
  ou.w = ((unsigned)f2b(o[7]) << 16) | f2b(o[6]);
  *reinterpret_cast<uint4*>(qp) = ou;
}

// ---------- merged o-proj + LN2 + FFN -------------------------------------
// R12: gemm_oln fused into ffn_fused. 64-row tiles, 512 blocks (2 blk/CU),
// 512 threads. LDS unchanged (81920 B, 2 blk/CU).
// Prologue A: o-proj C1 = attn_out @ WoT + bo (K=256, m97 2-barrier loop;
//   A-tile in Hs scratch, WoT in Wb; wave = 32row x 64col, accO[2][4]).
// Prologue B: y0 = xres + alpha*C1 -> xs linear (bf16, bit-identical f2b);
//   LN2 pass (8 rows/wave, identical math) writes y swizzled into xs.
// Main loop: R10-proven FFN (3-bit xs/Hs swizzle, Wb 2-bit swizzle,
//   counted vmcnt(2), 2 raw s_barriers/step, setprio). Prologue fully
//   drains vmcnt -> loop-entry ledger exact.
// Epilogue: d_out = bf2f(xs) + acc + b2 (PURE store; only writer of d_out;
//   no cross-replay state read -> replay-deterministic). Residual is bf16-y
//   (only numeric delta vs R11: <= |y|*2^-9).
// Eliminates: gemm_oln dispatch, ybf 33.6MB + yf32 67MB round-trips.
__global__ __launch_bounds__(512) void ffn_fused(
    const unsigned short* __restrict__ A, const unsigned short* __restrict__ Bt,
    const float* __restrict__ bo, const unsigned short* __restrict__ xres,
    const float* __restrict__ alpha_ptr,
    const float* __restrict__ g2, const float* __restrict__ b2ln,
    const unsigned short* __restrict__ W1T, const float* __restrict__ b1f,
    const unsigned short* __restrict__ W2T, const float* __restrict__ b2f,
    float* __restrict__ yio) {
  __shared__ unsigned short xs[64 * 256];   // 32768 B, slot-swizzled (3-bit)
  __shared__ unsigned short Hs[64 * 128];   // 16384 B (prologue: A-tile scratch)
  __shared__ unsigned short Wb[16384];      // 32 KB = 2 x 16KB halves
  int tid = threadIdx.x, lane = tid & 63, wave = tid >> 6;  // wave 0..7
  int l15 = lane & 15, quad = lane >> 4;
  int crow = lane >> 2;
  int ccs = (((lane & 3) ^ ((lane >> 3) & 3)) * 8);  // Wb pre-swizzled src col
  int rsw = ((quad ^ ((l15 >> 1) & 3)) * 8);         // Wb swizzled read col
  int sws = l15 & 7;         // xs/Hs 3-bit row-swizzle (row bases 8-aligned)
  int bm = blockIdx.x * 64;
  // ---- Prologue A: o-proj GEMM (64x256, K=256), wave = 32row x 64col ----
  {
    int wrO = (wave & 1) * 32, wcO = (wave >> 1) * 64;
    f32x4 accO[2][4] = {};
    for (int k0 = 0; k0 < 256; k0 += 32) {
      if (tid < 256)   // A-tile 64x32 -> Hs[0..2047] (linear, lane*8)
        async_copy16(A + (size_t)(bm + (tid >> 2)) * 256 + k0 + (tid & 3) * 8,
                     &Hs[tid * 8]);
      // WoT 256x32 -> Wb (linear), 2 chunks/thread
      async_copy16(Bt + (size_t)(tid >> 2) * 256 + k0 + (tid & 3) * 8,
                   &Wb[tid * 8]);
      async_copy16(Bt + (size_t)((tid >> 2) + 128) * 256 + k0 + (tid & 3) * 8,
                   &Wb[4096 + tid * 8]);
      __syncthreads();
      bf16x8 af[2], bfr[4];
#pragma unroll
      for (int mi = 0; mi < 2; ++mi)
        af[mi] = *reinterpret_cast<const bf16x8*>(
            &Hs[(wrO + mi * 16 + l15) * 32 + quad * 8]);
#pragma unroll
      for (int ni = 0; ni < 4; ++ni)
        bfr[ni] = *reinterpret_cast<const bf16x8*>(
            &Wb[(wcO + ni * 16 + l15) * 32 + quad * 8]);
#pragma unroll
      for (int mi = 0; mi < 2; ++mi)
#pragma unroll
        for (int ni = 0; ni < 4; ++ni)
          accO[mi][ni] = __builtin_amdgcn_mfma_f32_16x16x32_bf16(
              af[mi], bfr[ni], accO[mi][ni], 0, 0, 0);
      __syncthreads();
    }
    // ---- Prologue B: y0 -> xs linear; then LN2 -> xs swizzled ----
    float alpha = *alpha_ptr;
#pragma unroll
    for (int mi = 0; mi < 2; ++mi) {
#pragma unroll
      for (int ni = 0; ni < 4; ++ni) {
        int gcol = wcO + ni * 16 + l15;
        float bsf = bo[gcol];
#pragma unroll
        for (int r = 0; r < 4; ++r) {
          int lrow = wrO + mi * 16 + quad * 4 + r;
          float v = accO[mi][ni][r] + bsf;
          float y0 = bf2f(xres[(size_t)(bm + lrow) * 256 + gcol]) + alpha * v;
          xs[lrow * 256 + gcol] = f2b(y0);
        }
      }
    }
    __syncthreads();
    for (int it = 0; it < 8; ++it) {
      int row = wave * 8 + it;
      ushort4 u = *reinterpret_cast<const ushort4*>(&xs[row * 256 + lane * 4]);
      float v0 = bf2f(u.x), v1 = bf2f(u.y), v2 = bf2f(u.z), v3 = bf2f(u.w);
      float s = v0 + v1 + v2 + v3;
      float q = v0 * v0 + v1 * v1 + v2 * v2 + v3 * v3;
#pragma unroll
      for (int off = 1; off < 64; off <<= 1) {
        s += __shfl_xor(s, off);
        q += __shfl_xor(q, off);
      }
      float mean = s * (1.0f / 256.0f);
      float var  = q * (1.0f / 256.0f) - mean * mean;
      float rstd = rsqrtf(var + 1e-5f);
      float4 gv = *reinterpret_cast<const float4*>(g2 + lane * 4);
      float4 bv = *reinterpret_cast<const float4*>(b2ln + lane * 4);
      ushort4 ob;
      ob.x = f2b((v0 - mean) * rstd * gv.x + bv.x);
      ob.y = f2b((v1 - mean) * rstd * gv.y + bv.y);
      ob.z = f2b((v2 - mean) * rstd * gv.z + bv.z);
      ob.w = f2b((v3 - mean) * rstd * gv.w + bv.w);
      // swizzled write: cols lane*4..+3 live in slot (lane>>1)^(row&7)
      int slot = (lane >> 1) ^ (row & 7);
      *reinterpret_cast<ushort4*>(&xs[row * 256 + slot * 8 + (lane & 1) * 4]) = ob;
    }
    __syncthreads();   // xs swizzled y visible to all; vmcnt fully drained
  }
  // ---- Main FFN loop (R10-proven, unchanged) ----
  int wm2 = (wave & 1) * 32, wn2 = (wave >> 1) * 64;   // phase2 tile
  int wh1 = (wave & 1) * 64, wr1 = (wave >> 1) * 16;   // phase1 tile
  int row1 = wr1 + l15;                                 // phase1 xs row
  const unsigned short* w1p = W1T + (size_t)(wave * 16 + crow) * 256 + ccs;
  const unsigned short* w2p = W2T + (size_t)(wave * 32 + crow) * 1024 + ccs;
  auto stage_step = [&](int p2, int half) {
    unsigned short* buf = &Wb[half * 8192];
    if (p2 < 4) {
      async_copy16(w1p,      &buf[wave * 512]);
      async_copy16(w1p + 32, &buf[4096 + wave * 512]);
      w1p += 64;
      if (p2 == 3) w1p += 32512;         // next chunk: +32768 total
    } else {
      async_copy16(w2p,          &buf[wave * 1024]);
      async_copy16(w2p + 16384,  &buf[wave * 1024 + 512]);
      w2p += 32;                          // 4 steps = +128 = chunk stride
    }
  };
  f32x4 acc[2][4] = {};
  stage_step(0, 0); stage_step(1, 1);
  for (int c = 0; c < 8; ++c) {
    f32x4 acc1[4] = {};
#pragma unroll
    for (int p = 0; p < 8; ++p) {
      // ledger: outstanding = {st:2, st+1:2} except final step ({63:2})
      if (p == 7 && c == 7)
        asm volatile("s_waitcnt vmcnt(0) lgkmcnt(0)" ::: "memory");
      else
        asm volatile("s_waitcnt vmcnt(2) lgkmcnt(0)" ::: "memory");
      __builtin_amdgcn_s_barrier();
      __builtin_amdgcn_sched_barrier(0);
      const unsigned short* buf = &Wb[(p & 1) * 8192];
      if (p < 4) {
#pragma unroll
        for (int sl = 0; sl < 2; ++sl) {
          int k = p * 64 + sl * 32;
          bf16x8 af[4];
#pragma unroll
          for (int mi = 0; mi < 4; ++mi)
            af[mi] = *reinterpret_cast<const bf16x8*>(
                &buf[sl * 4096 + (wh1 + mi * 16 + l15) * 32 + rsw]);
          bf16x8 bx = *reinterpret_cast<const bf16x8*>(
              &xs[row1 * 256 + (((k >> 3) + quad) ^ sws) * 8]);
          __builtin_amdgcn_s_setprio(1);
#pragma unroll
          for (int mi = 0; mi < 4; ++mi)
            acc1[mi] = __builtin_amdgcn_mfma_f32_16x16x32_bf16(
                af[mi], bx, acc1[mi], 0, 0, 0);
          __builtin_amdgcn_s_setprio(0);
        }
        if (p == 3) {   // GELU + bias -> Hs (phase1 of chunk c complete)
#pragma unroll
          for (int mi = 0; mi < 4; ++mi) {
            int hb = wh1 + mi * 16 + quad * 4;
            float b0 = b1f[c * 128 + hb],      b1v = b1f[c * 128 + hb + 1];
            float b2v = b1f[c * 128 + hb + 2], b3 = b1f[c * 128 + hb + 3];
            ushort4 hw;
            hw.x = f2b(gelu_t(acc1[mi][0] + b0));
            hw.y = f2b(gelu_t(acc1[mi][1] + b1v));
            hw.z = f2b(gelu_t(acc1[mi][2] + b2v));
            hw.w = f2b(gelu_t(acc1[mi][3] + b3));
            *reinterpret_cast<ushort4*>(
                &Hs[row1 * 128 + (((hb >> 3) ^ sws) * 8) + (hb & 7)]) = hw;
          }
        }
      } else {
        int kk = (p - 4) * 32;
        bf16x8 af[2], bfr[4];
#pragma unroll
        for (int mi = 0; mi < 2; ++mi) {
          int hrow = wm2 + mi * 16 + l15;
          af[mi] = *reinterpret_cast<const bf16x8*>(
              &Hs[hrow * 128 + (((kk >> 3) + quad) ^ sws) * 8]);
        }
#pragma unroll
        for (int ni = 0; ni < 4; ++ni)
          bfr[ni] = *reinterpret_cast<const bf16x8*>(
              &buf[(wn2 + ni * 16 + l15) * 32 + rsw]);
        __builtin_amdgcn_s_setprio(1);
#pragma unroll
        for (int mi = 0; mi < 2; ++mi)
#pragma unroll
          for (int ni = 0; ni < 4; ++ni)
            acc[mi][ni] = __builtin_amdgcn_mfma_f32_16x16x32_bf16(
                af[mi], bfr[ni], acc[mi][ni], 0, 0, 0);
        __builtin_amdgcn_s_setprio(0);
      }
      __builtin_amdgcn_sched_barrier(0);
      __builtin_amdgcn_s_barrier();
      __builtin_amdgcn_sched_barrier(0);
      if (c < 7 || p < 6)
        stage_step((p + 2) & 7, p & 1);
    }
  }
  // ---- epilogue: out = y(residual from xs, bf16) + acc + b2 (pure store) --
#pragma unroll
  for (int mi = 0; mi < 2; ++mi)
#pragma unroll
    for (int ni = 0; ni < 4; ++ni) {
      int col = wn2 + ni * 16 + l15;
      float bs = b2f[col];
#pragma unroll
      for (int r = 0; r < 4; ++r) {
        int lrow = wm2 + mi * 16 + quad * 4 + r;
        float resid = bf2f(xs[lrow * 256 + (((col >> 3) ^ (lrow & 7)) * 8) + (col & 7)]);
        size_t oi = (size_t)(bm + lrow) * 256 + col;
        yio[oi] = resid + acc[mi][ni][r] + bs;
      }
    }
}

extern "C" void kernel_launch(void* const* d_in, const int* in_sizes, int n_in,
                              void* d_out, int out_size, void* d_ws, size_t ws_size,
                              hipStream_t stream) {
  const float* visual = (const float*)d_in[0];
  const float* text   = (const float*)d_in[1];
  const float* Wq  = (const float*)d_in[2];
  const float* bq  = (const float*)d_in[3];
  const float* Wk  = (const float*)d_in[4];
  const float* bk  = (const float*)d_in[5];
  const float* Wv  = (const float*)d_in[6];
  const float* bv  = (const float*)d_in[7];
  const float* Wo  = (const float*)d_in[8];
  const float* bo  = (const float*)d_in[9];
  const float* g1  = (const float*)d_in[10];
  const float* b1  = (const float*)d_in[11];
  const float* g2  = (const float*)d_in[12];
  const float* b2  = (const float*)d_in[13];
  const float* W1  = (const float*)d_in[14];
  const float* bf1 = (const float*)d_in[15];
  const float* W2  = (const float*)d_in[16];
  const float* bff2 = (const float*)d_in[17];
  const float* lsc = (const float*)d_in[18];
  const float* alp = (const float*)d_in[19];

  char* ws = (char*)d_ws;
  size_t off = 0;
  auto alloc = [&](size_t bytes) -> char* {
    char* p = ws + off;
    off += (bytes + 255) & ~(size_t)255;
    return p;
  };
  unsigned short* WqT = (unsigned short*)alloc((size_t)65536 * 2);
  unsigned short* WkT = (unsigned short*)alloc((size_t)131072 * 2);  // contiguous
  unsigned short* WvT = (unsigned short*)alloc((size_t)131072 * 2);  // with WkT
  unsigned short* WoT = (unsigned short*)alloc((size_t)65536 * 2);
  unsigned short* W1T = (unsigned short*)alloc((size_t)262144 * 2);
  unsigned short* W2T = (unsigned short*)alloc((size_t)262144 * 2);
  float*          bkv  = (float*)alloc(512 * 4);
  float*          kbuf = (float*)alloc((size_t)BT_ * CV_ * 4);
  float*          vbuf = (float*)alloc((size_t)BT_ * CV_ * 4);
  float*          padb = (float*)alloc((size_t)BT_ * 4);
  char* U = ws + off;                      // total ws ~= 36.3 MB
  unsigned short* xbuf = (unsigned short*)U;
  unsigned short* qbuf = (unsigned short*)(U + 16777216);
  float*          ybuf = (float*)d_out;

  // 1. prep: LN1 + LDS-tiled weight convT + kv bias + pad mask
  prep_kernel<<<8571, 256, 0, stream>>>(visual, g1, b1, xbuf,
                                        Wq, Wk, Wv, Wo, W1, W2,
                                        WqT, WkT, WvT, WoT, W1T, W2T,
                                        bk, bv, bkv, text, padb);
  // 2. q-proj (128x64 tiles, 4 blk/CU) + kv GEMM merged
  qkv_kernel<<<1104, 256, 0, stream>>>(xbuf, WqT, bq, qbuf,
                                       text, WkT, bkv, kbuf, vbuf);
  // 3. attention v3: qbuf -> qbuf in place
  attn_kernel<<<dim3(64, NH_, NB), 256, 0, stream>>>(qbuf, kbuf, vbuf, padb, lsc);
  // 4. merged o-proj + LN2 + FFN: qbuf + xbuf -> d_out (sole d_out writer)
  ffn_fused<<<512, 512, 0, stream>>>(qbuf, WoT, bo, xbuf, alp, g2, b2,
                                     W1T, bf1, W2T, bff2, ybuf);
}